// Round 1
// baseline (887.291 us; speedup 1.0000x reference)
//
#include <hip/hip_runtime.h>
#include <stdint.h>

#define DSR   0.90483741803595952f   // exp(-1/10)
#define DREF  0.36787944117144233f   // exp(-1)
#define THETA 10.0f
#define REFAMP 20.0f                 // SCALE_REF * THETA

#define NB 16
#define TT 500
#define TP 512
#define F1 6300
#define KP 6336      // K padded (multiple of 64)
#define O1 1024
#define NC 8192      // NB * TP columns
#define FT 156
#define OT 50
#define O2 10
#define OF 20

typedef __attribute__((ext_vector_type(8))) short    short8;
typedef __attribute__((ext_vector_type(4))) float    f32x4;
typedef __attribute__((ext_vector_type(4))) unsigned short ushort4v;

static __device__ __forceinline__ unsigned short f2bf(float x) {
  unsigned u = __float_as_uint(x);
  unsigned r = (u + 0x7FFFu + ((u >> 16) & 1u)) >> 16;   // RNE
  return (unsigned short)r;
}

// ---------------- K0a: split Wv1 into bf16 hi/lo, zero-pad K to 6336 --------
__global__ void k_splitw(const float* __restrict__ W, unsigned short* __restrict__ whi,
                         unsigned short* __restrict__ wlo) {
  int idx = blockIdx.x * 256 + threadIdx.x;
  if (idx >= O1 * KP) return;
  int o = idx / KP, f = idx - o * KP;
  float w = (f < F1) ? W[o * F1 + f] : 0.0f;
  unsigned short h = f2bf(w);
  float hf = __uint_as_float((unsigned)h << 16);
  unsigned short l = f2bf(w - hf);
  whi[idx] = h;
  wlo[idx] = l;
}

// ---------------- K0b: transpose xv (n,f,t) -> xbT[(n*512+t)*6336 + f] bf16 --
__global__ void k_xpose(const float* __restrict__ xv, unsigned short* __restrict__ xbT) {
  __shared__ unsigned short tile[64][68];
  int ft = blockIdx.x, tt = blockIdx.y, n = blockIdx.z;
  int tx = threadIdx.x & 63, ty = threadIdx.x >> 6;  // 64 x 4
  int f0 = ft * 64, t0 = tt * 64;
#pragma unroll
  for (int i = 0; i < 16; ++i) {
    int fr = ty * 16 + i;
    int f = f0 + fr, t = t0 + tx;
    float v = (f < F1 && t < TT) ? xv[((size_t)n * F1 + f) * TT + t] : 0.0f;
    tile[fr][tx] = f2bf(v);
  }
  __syncthreads();
#pragma unroll
  for (int i = 0; i < 16; ++i) {
    int tr = ty * 16 + i;
    xbT[((size_t)n * TP + (t0 + tr)) * KP + (f0 + tx)] = tile[tx][tr];
  }
}

// ---------------- K1: tactile: dense(Wt,xt) -> psp -> spike -> s_tact -------
__global__ void __launch_bounds__(512) k_tact(const float* __restrict__ xt,
                                              const float* __restrict__ Wt,
                                              float* __restrict__ s_tact) {
  __shared__ float at_s[25 * TP];
  int n = blockIdx.x >> 1, half = blockIdx.x & 1;
  int t = threadIdx.x;
  if (t < TT) {
    float acc[25];
#pragma unroll
    for (int o = 0; o < 25; ++o) acc[o] = 0.f;
    for (int f = 0; f < FT; ++f) {
      float x = xt[((size_t)n * FT + f) * TT + t];
      if (x != 0.f) {
#pragma unroll
        for (int o = 0; o < 25; ++o)
          acc[o] += Wt[(half * 25 + o) * FT + f] * x;
      }
    }
#pragma unroll
    for (int o = 0; o < 25; ++o) at_s[o * TP + t] = acc[o];
  }
  __syncthreads();
  if (t < 25) {
    float p = 0.f, r = 0.f;
    int ob = half * 25 + t;
    for (int i = 0; i < TT; ++i) {
      float u = at_s[t * TP + i];
      p = DSR * p + u;
      float v = p + r;
      float s = (v >= THETA) ? 1.0f : 0.0f;
      r = DREF * (r - REFAMP * s);
      s_tact[((size_t)n * OT + ob) * TT + i] = s;
    }
  }
}

// ---------------- K2: GEMM  C(1024x8192) = [Whi;Wlo](1024xK) * xbT^T --------
static __device__ __forceinline__ int swz(int i) { return i ^ ((i >> 3) & 7); }

__global__ void __launch_bounds__(256) k_gemm(const unsigned short* __restrict__ whi,
                                              const unsigned short* __restrict__ wlo,
                                              const unsigned short* __restrict__ BT,
                                              float* __restrict__ C) {
  __shared__ unsigned short As[128 * 32];
  __shared__ unsigned short Bs[128 * 32];
  int tid = threadIdx.x;
  int gx = blockIdx.x, gy = blockIdx.y;
  int w = tid >> 6, lane = tid & 63;
  int wr = w >> 1, wc = w & 1;
  int lr = lane & 15, lg = lane >> 4;

  f32x4 acc[4][4];
#pragma unroll
  for (int m = 0; m < 4; ++m)
#pragma unroll
    for (int nn = 0; nn < 4; ++nn) acc[m][nn] = (f32x4)0.f;

  int r0 = tid >> 2, q = tid & 3;
  size_t aoff0 = ((size_t)(gy * 128 + r0)) * KP + q * 8;
  size_t aoff1 = ((size_t)(gy * 128 + 64 + r0)) * KP + q * 8;
  size_t boff0 = ((size_t)(gx * 128 + r0)) * KP + q * 8;
  size_t boff1 = ((size_t)(gx * 128 + 64 + r0)) * KP + q * 8;
  short8* As8 = (short8*)As;
  short8* Bs8 = (short8*)Bs;
  int s0 = swz(tid), s1 = swz(256 + tid);

  for (int pass = 0; pass < 2; ++pass) {
    const unsigned short* A = pass ? wlo : whi;
    for (int ks = 0; ks < KP / 32; ++ks) {
      size_t ko = (size_t)ks * 32;
      short8 a0 = *(const short8*)(A + aoff0 + ko);
      short8 a1 = *(const short8*)(A + aoff1 + ko);
      short8 b0 = *(const short8*)(BT + boff0 + ko);
      short8 b1 = *(const short8*)(BT + boff1 + ko);
      As8[s0] = a0; As8[s1] = a1;
      Bs8[s0] = b0; Bs8[s1] = b1;
      __syncthreads();
      short8 aF[4], bF[4];
#pragma unroll
      for (int m = 0; m < 4; ++m)
        aF[m] = As8[swz((wr * 64 + m * 16 + lr) * 4 + lg)];
#pragma unroll
      for (int nn = 0; nn < 4; ++nn)
        bF[nn] = Bs8[swz((wc * 64 + nn * 16 + lr) * 4 + lg)];
#pragma unroll
      for (int m = 0; m < 4; ++m)
#pragma unroll
        for (int nn = 0; nn < 4; ++nn)
          acc[m][nn] = __builtin_amdgcn_mfma_f32_16x16x32_bf16(aF[m], bF[nn], acc[m][nn], 0, 0, 0);
      __syncthreads();
    }
  }
#pragma unroll
  for (int m = 0; m < 4; ++m)
#pragma unroll
    for (int nn = 0; nn < 4; ++nn) {
      int o = gy * 128 + wr * 64 + m * 16 + lg * 4;
      int c = gx * 128 + wc * 64 + nn * 16 + lr;
#pragma unroll
      for (int reg = 0; reg < 4; ++reg)
        C[(size_t)(o + reg) * NC + c] = acc[m][nn][reg];
    }
}

// ---------------- K3: vision stage-1 psp+spike -> sv1 (bf16 binary) ---------
__global__ void k_spk1(const float* __restrict__ C, unsigned short* __restrict__ sv1) {
  int g = blockIdx.x * 256 + threadIdx.x;   // 0..16383
  int n = g >> 10, o = g & 1023;
  const f32x4* u4p = (const f32x4*)(C + (size_t)o * NC + n * TP);
  ushort4v* out4 = (ushort4v*)(sv1 + ((size_t)n * O1 + o) * TT);
  float p = 0.f, r = 0.f;
  for (int i = 0; i < TT / 4; ++i) {
    f32x4 u4 = u4p[i];
    ushort4v s4;
#pragma unroll
    for (int j = 0; j < 4; ++j) {
      p = DSR * p + u4[j];
      float v = p + r;
      float s = (v >= THETA) ? 1.0f : 0.0f;
      r = DREF * (r - REFAMP * s);
      s4[j] = (v >= THETA) ? (unsigned short)0x3F80 : (unsigned short)0;
    }
    out4[i] = s4;
  }
}

// ---------------- K45: head: Wv2 dense -> psp+spike -> concat -> Wf -> out --
__global__ void __launch_bounds__(512) k_head(const unsigned short* __restrict__ sv1,
                                              const float* __restrict__ s_tact,
                                              const float* __restrict__ Wv2,
                                              const float* __restrict__ Wf,
                                              float* __restrict__ out) {
  __shared__ float a2_s[O2 * TP];   // 20KB
  __shared__ float af_s[OF * TP];   // 41KB
  int n = blockIdx.x;
  int t = threadIdx.x;
  // phase A: a2 = Wv2 @ sv1
  if (t < TT) {
    float acc[O2];
#pragma unroll
    for (int o = 0; o < O2; ++o) acc[o] = 0.f;
    for (int f = 0; f < O1; ++f) {
      unsigned short sb = sv1[((size_t)n * O1 + f) * TT + t];
      if (sb) {
#pragma unroll
        for (int o = 0; o < O2; ++o)
          acc[o] += Wv2[o * O1 + f];
      }
    }
#pragma unroll
    for (int o = 0; o < O2; ++o) a2_s[o * TP + t] = acc[o];
  }
  __syncthreads();
  // phase B: vis psp+spike (overwrite a2_s with spikes)
  if (t < O2) {
    float p = 0.f, r = 0.f;
    for (int i = 0; i < TT; ++i) {
      float u = a2_s[t * TP + i];
      p = DSR * p + u;
      float v = p + r;
      float s = (v >= THETA) ? 1.f : 0.f;
      r = DREF * (r - REFAMP * s);
      a2_s[t * TP + i] = s;
    }
  }
  __syncthreads();
  // phase C: af = Wf @ [s_tact ; s_vis]
  if (t < TT) {
    float acc[OF];
#pragma unroll
    for (int o = 0; o < OF; ++o) acc[o] = 0.f;
    for (int f = 0; f < OT; ++f) {
      float s = s_tact[((size_t)n * OT + f) * TT + t];
      if (s != 0.f) {
#pragma unroll
        for (int o = 0; o < OF; ++o)
          acc[o] += Wf[o * 60 + f] * s;
      }
    }
#pragma unroll
    for (int f = 0; f < O2; ++f) {
      float s = a2_s[f * TP + t];
      if (s != 0.f) {
#pragma unroll
        for (int o = 0; o < OF; ++o)
          acc[o] += Wf[o * 60 + OT + f] * s;
      }
    }
#pragma unroll
    for (int o = 0; o < OF; ++o) af_s[o * TP + t] = acc[o];
  }
  __syncthreads();
  // phase D: final psp+spike -> out
  if (t < OF) {
    float p = 0.f, r = 0.f;
    for (int i = 0; i < TT; ++i) {
      float u = af_s[t * TP + i];
      p = DSR * p + u;
      float v = p + r;
      float s = (v >= THETA) ? 1.f : 0.f;
      r = DREF * (r - REFAMP * s);
      out[((size_t)n * OF + t) * TT + i] = s;
    }
  }
}

extern "C" void kernel_launch(void* const* d_in, const int* in_sizes, int n_in,
                              void* d_out, int out_size, void* d_ws, size_t ws_size,
                              hipStream_t stream) {
  (void)in_sizes; (void)n_in; (void)out_size; (void)ws_size;
  const float* xt  = (const float*)d_in[0];
  const float* xv  = (const float*)d_in[1];
  const float* Wt  = (const float*)d_in[2];
  const float* Wv1 = (const float*)d_in[3];
  const float* Wv2 = (const float*)d_in[4];
  const float* Wf  = (const float*)d_in[5];
  float* out = (float*)d_out;

  char* ws = (char*)d_ws;
  size_t off = 0;
  auto carve = [&](size_t bytes) {
    char* p = ws + off;
    off += (bytes + 255) & ~(size_t)255;
    return p;
  };
  unsigned short* whi    = (unsigned short*)carve((size_t)O1 * KP * 2);
  unsigned short* wlo    = (unsigned short*)carve((size_t)O1 * KP * 2);
  unsigned short* xbT    = (unsigned short*)carve((size_t)NB * TP * KP * 2);
  float*          a1     = (float*)carve((size_t)O1 * NC * 4);
  unsigned short* sv1    = (unsigned short*)carve((size_t)NB * O1 * TT * 2);
  float*          stact  = (float*)carve((size_t)NB * OT * TT * 4);

  k_splitw<<<dim3((O1 * KP + 255) / 256), dim3(256), 0, stream>>>(Wv1, whi, wlo);
  k_xpose<<<dim3(KP / 64, TP / 64, NB), dim3(256), 0, stream>>>(xv, xbT);
  k_tact<<<dim3(NB * 2), dim3(512), 0, stream>>>(xt, Wt, stact);
  k_gemm<<<dim3(NC / 128, O1 / 128), dim3(256), 0, stream>>>(whi, wlo, xbT, a1);
  k_spk1<<<dim3(64), dim3(256), 0, stream>>>(a1, sv1);
  k_head<<<dim3(NB), dim3(512), 0, stream>>>(sv1, stact, Wv2, Wf, out);
}

// Round 2
// 624.493 us; speedup vs baseline: 1.4208x; 1.4208x over previous
//
#include <hip/hip_runtime.h>
#include <stdint.h>

#define DSR   0.90483741803595952f   // exp(-1/10)
#define DREF  0.36787944117144233f   // exp(-1)
#define THETA 10.0f
#define REFAMP 20.0f                 // SCALE_REF * THETA

#define NB 16
#define TT 500
#define TP 512
#define F1 6300
#define KP 6336      // K padded (multiple of 64)
#define O1 1024
#define NC 8192      // NB * TP columns
#define FT 156
#define OT 50
#define O2 10
#define OF 20

typedef __attribute__((ext_vector_type(8))) short    short8;
typedef __attribute__((ext_vector_type(4))) float    f32x4;
typedef __attribute__((ext_vector_type(4))) unsigned short ushort4v;

#define GLL16(g, l) __builtin_amdgcn_global_load_lds( \
    (const __attribute__((address_space(1))) void*)(g), \
    (__attribute__((address_space(3))) void*)(l), 16, 0, 0)

static __device__ __forceinline__ unsigned short f2bf(float x) {
  unsigned u = __float_as_uint(x);
  unsigned r = (u + 0x7FFFu + ((u >> 16) & 1u)) >> 16;   // RNE
  return (unsigned short)r;
}
static __device__ __forceinline__ float bf2f(unsigned short b) {
  return __uint_as_float((unsigned)b << 16);
}

// ---------------- K0a: split Wv1 into bf16 hi/lo, zero-pad K to 6336 --------
__global__ void k_splitw(const float* __restrict__ W, unsigned short* __restrict__ whi,
                         unsigned short* __restrict__ wlo) {
  int idx = blockIdx.x * 256 + threadIdx.x;
  if (idx >= O1 * KP) return;
  int o = idx / KP, f = idx - o * KP;
  float w = (f < F1) ? W[o * F1 + f] : 0.0f;
  unsigned short h = f2bf(w);
  float hf = bf2f(h);
  unsigned short l = f2bf(w - hf);
  whi[idx] = h;
  wlo[idx] = l;
}

// ---------------- K0b: transpose xv (n,f,t) -> xbT[(n*512+t)*6336 + f] bf16 --
__global__ void k_xpose(const float* __restrict__ xv, unsigned short* __restrict__ xbT) {
  __shared__ unsigned short tile[64][68];
  int ft = blockIdx.x, tt = blockIdx.y, n = blockIdx.z;
  int tx = threadIdx.x & 63, ty = threadIdx.x >> 6;  // 64 x 4
  int f0 = ft * 64, t0 = tt * 64;
#pragma unroll
  for (int i = 0; i < 16; ++i) {
    int fr = ty * 16 + i;
    int f = f0 + fr, t = t0 + tx;
    float v = (f < F1 && t < TT) ? xv[((size_t)n * F1 + f) * TT + t] : 0.0f;
    tile[fr][tx] = f2bf(v);
  }
  __syncthreads();
#pragma unroll
  for (int i = 0; i < 16; ++i) {
    int tr = ty * 16 + i;
    xbT[((size_t)n * TP + (t0 + tr)) * KP + (f0 + tx)] = tile[tx][tr];
  }
}

// ---------------- K1: tactile: dense(Wt,xt) -> psp -> spike -> s_tact -------
__global__ void __launch_bounds__(512) k_tact(const float* __restrict__ xt,
                                              const float* __restrict__ Wt,
                                              float* __restrict__ s_tact) {
  __shared__ float at_s[25 * TP];
  int n = blockIdx.x >> 1, half = blockIdx.x & 1;
  int t = threadIdx.x;
  if (t < TT) {
    float acc[25];
#pragma unroll
    for (int o = 0; o < 25; ++o) acc[o] = 0.f;
    for (int f = 0; f < FT; ++f) {
      float x = xt[((size_t)n * FT + f) * TT + t];
      if (x != 0.f) {
#pragma unroll
        for (int o = 0; o < 25; ++o)
          acc[o] += Wt[(half * 25 + o) * FT + f] * x;
      }
    }
#pragma unroll
    for (int o = 0; o < 25; ++o) at_s[o * TP + t] = acc[o];
  }
  __syncthreads();
  if (t < 25) {
    float p = 0.f, r = 0.f;
    int ob = half * 25 + t;
    for (int i = 0; i < TT; ++i) {
      float u = at_s[t * TP + i];
      p = DSR * p + u;
      float v = p + r;
      float s = (v >= THETA) ? 1.0f : 0.0f;
      r = DREF * (r - REFAMP * s);
      s_tact[((size_t)n * OT + ob) * TT + i] = s;
    }
  }
}

// ---------------- K2: GEMM  C(1024x8192) = [Whi+Wlo](1024xK) * xbT^T --------
// 128x128 tile, BK=32, 256 thr, global_load_lds(16B) staging, fused hi/lo.
// LDS layout: granule(16B) at physical (r, m) holds logical k-granule
// s = (m ^ (r>>1)) & 3  (XOR involution; pre-swizzled on the GLOBAL source,
// LDS dest stays linear as global_load_lds requires).
__global__ void __launch_bounds__(256) k_gemm(const unsigned short* __restrict__ whi,
                                              const unsigned short* __restrict__ wlo,
                                              const unsigned short* __restrict__ BT,
                                              float* __restrict__ C) {
  __shared__ unsigned short Ah[128 * 32];
  __shared__ unsigned short Al[128 * 32];
  __shared__ unsigned short Bs[128 * 32];
  int tid = threadIdx.x;
  int gx = blockIdx.x, gy = blockIdx.y;
  int wave = tid >> 6, lane = tid & 63;
  int wr = wave >> 1, wc = wave & 1;
  int lr = lane & 15, lg = lane >> 4;

  f32x4 acc[4][4];
#pragma unroll
  for (int m = 0; m < 4; ++m)
#pragma unroll
    for (int nn = 0; nn < 4; ++nn) acc[m][nn] = (f32x4)0.f;

  // staging: physical granule p = round*256 + tid; r=p>>2, m=p&3
  int r0 = tid >> 2, m0 = tid & 3;
  int s0 = (m0 ^ (r0 >> 1)) & 3;
  int p1 = 256 + tid;
  int r1 = p1 >> 2, m1 = p1 & 3;
  int s1 = (m1 ^ (r1 >> 1)) & 3;
  size_t ga0 = (size_t)(gy * 128 + r0) * KP + s0 * 8;
  size_t ga1 = (size_t)(gy * 128 + r1) * KP + s1 * 8;
  size_t gb0 = (size_t)(gx * 128 + r0) * KP + s0 * 8;
  size_t gb1 = (size_t)(gx * 128 + r1) * KP + s1 * 8;
  unsigned lb0 = (unsigned)(wave * 64) * 16u;        // byte offset, round 0
  unsigned lb1 = 4096u + (unsigned)(wave * 64) * 16u; // round 1

  // fragment physical granule indices (per-lane, swizzled)
  int physA[4], physB[4];
#pragma unroll
  for (int m = 0; m < 4; ++m) {
    int r = wr * 64 + m * 16 + lr;
    physA[m] = r * 4 + ((lg ^ (r >> 1)) & 3);
  }
#pragma unroll
  for (int nn = 0; nn < 4; ++nn) {
    int r = wc * 64 + nn * 16 + lr;
    physB[nn] = r * 4 + ((lg ^ (r >> 1)) & 3);
  }

  for (int ks = 0; ks < KP / 32; ++ks) {
    size_t ko = (size_t)ks * 32;
    GLL16(whi + ga0 + ko, (char*)Ah + lb0);
    GLL16(whi + ga1 + ko, (char*)Ah + lb1);
    GLL16(wlo + ga0 + ko, (char*)Al + lb0);
    GLL16(wlo + ga1 + ko, (char*)Al + lb1);
    GLL16(BT + gb0 + ko, (char*)Bs + lb0);
    GLL16(BT + gb1 + ko, (char*)Bs + lb1);
    __syncthreads();
    short8 ah[4], al[4], bf[4];
#pragma unroll
    for (int m = 0; m < 4; ++m) {
      ah[m] = *(const short8*)(Ah + physA[m] * 8);
      al[m] = *(const short8*)(Al + physA[m] * 8);
    }
#pragma unroll
    for (int nn = 0; nn < 4; ++nn)
      bf[nn] = *(const short8*)(Bs + physB[nn] * 8);
#pragma unroll
    for (int m = 0; m < 4; ++m)
#pragma unroll
      for (int nn = 0; nn < 4; ++nn) {
        acc[m][nn] = __builtin_amdgcn_mfma_f32_16x16x32_bf16(ah[m], bf[nn], acc[m][nn], 0, 0, 0);
        acc[m][nn] = __builtin_amdgcn_mfma_f32_16x16x32_bf16(al[m], bf[nn], acc[m][nn], 0, 0, 0);
      }
    __syncthreads();
  }
#pragma unroll
  for (int m = 0; m < 4; ++m)
#pragma unroll
    for (int nn = 0; nn < 4; ++nn) {
      int o = gy * 128 + wr * 64 + m * 16 + lg * 4;
      int c = gx * 128 + wc * 64 + nn * 16 + lr;
#pragma unroll
      for (int reg = 0; reg < 4; ++reg)
        C[(size_t)(o + reg) * NC + c] = acc[m][nn][reg];
    }
}

// ---------------- K3: vision stage-1 psp+spike -> sv1 (bf16 binary) ---------
__global__ void k_spk1(const float* __restrict__ C, unsigned short* __restrict__ sv1) {
  int g = blockIdx.x * 256 + threadIdx.x;   // 0..16383
  int n = g >> 10, o = g & 1023;
  const f32x4* u4p = (const f32x4*)(C + (size_t)o * NC + n * TP);
  ushort4v* out4 = (ushort4v*)(sv1 + ((size_t)n * O1 + o) * TT);
  float p = 0.f, r = 0.f;
  for (int i = 0; i < TT / 4; ++i) {
    f32x4 u4 = u4p[i];
    ushort4v s4;
#pragma unroll
    for (int j = 0; j < 4; ++j) {
      p = DSR * p + u4[j];
      float v = p + r;
      float s = (v >= THETA) ? 1.0f : 0.0f;
      r = DREF * (r - REFAMP * s);
      s4[j] = (v >= THETA) ? (unsigned short)0x3F80 : (unsigned short)0;
    }
    out4[i] = s4;
  }
}

// ---------------- K4: a2[n][o][t] = Wv2 @ sv1 (parallel, coalesced) ---------
__global__ void __launch_bounds__(256) k_vis2(const unsigned short* __restrict__ sv1,
                                              const float* __restrict__ Wv2,
                                              float* __restrict__ a2) {
  __shared__ float w2[O2 * O1];        // 40 KB
  __shared__ float red[3][O2][64];     // 7.5 KB
  int n = blockIdx.x, t0 = blockIdx.y * 64;
  int tid = threadIdx.x, lane = tid & 63, w = tid >> 6;
  for (int i = tid; i < O2 * O1; i += 256) w2[i] = Wv2[i];
  __syncthreads();
  int t = t0 + lane;
  bool tv = t < TT;
  const unsigned short* sp = sv1 + ((size_t)n * O1 + w * 256) * TT + (tv ? t : 0);
  float acc[O2];
#pragma unroll
  for (int o = 0; o < O2; ++o) acc[o] = 0.f;
  for (int f = 0; f < 256; ++f) {
    float s = tv ? bf2f(sp[(size_t)f * TT]) : 0.f;
    int fg = w * 256 + f;
#pragma unroll
    for (int o = 0; o < O2; ++o) acc[o] = fmaf(w2[o * O1 + fg], s, acc[o]);
  }
  if (w) {
#pragma unroll
    for (int o = 0; o < O2; ++o) red[w - 1][o][lane] = acc[o];
  }
  __syncthreads();
  if (w == 0 && tv) {
#pragma unroll
    for (int o = 0; o < O2; ++o) {
      float v = acc[o] + red[0][o][lane] + red[1][o][lane] + red[2][o][lane];
      a2[((size_t)n * O2 + o) * TT + t] = v;
    }
  }
}

// ---------------- K5: head: psp+spike(a2) -> concat -> Wf -> psp+spike ------
__global__ void __launch_bounds__(512) k_finish(const float* __restrict__ a2,
                                                const float* __restrict__ s_tact,
                                                const float* __restrict__ Wf,
                                                float* __restrict__ out) {
  __shared__ float svis[O2][TP];   // 20 KB
  __shared__ float af[OF][TP];     // 41 KB
  int n = blockIdx.x, t = threadIdx.x;
  // phase B: vis psp+spike
  if (t < O2) {
    const float* ap = a2 + ((size_t)n * O2 + t) * TT;
    float p = 0.f, r = 0.f;
    for (int i = 0; i < TT; ++i) {
      float u = ap[i];
      p = DSR * p + u;
      float v = p + r;
      float s = (v >= THETA) ? 1.f : 0.f;
      r = DREF * (r - REFAMP * s);
      svis[t][i] = s;
    }
  }
  __syncthreads();
  // phase C: af = Wf @ [s_tact ; s_vis]
  if (t < TT) {
    float acc[OF];
#pragma unroll
    for (int o = 0; o < OF; ++o) acc[o] = 0.f;
    for (int f = 0; f < OT; ++f) {
      float s = s_tact[((size_t)n * OT + f) * TT + t];
      if (s != 0.f) {
#pragma unroll
        for (int o = 0; o < OF; ++o)
          acc[o] += Wf[o * 60 + f];
      }
    }
#pragma unroll
    for (int f = 0; f < O2; ++f) {
      float s = svis[f][t];
      if (s != 0.f) {
#pragma unroll
        for (int o = 0; o < OF; ++o)
          acc[o] += Wf[o * 60 + OT + f];
      }
    }
#pragma unroll
    for (int o = 0; o < OF; ++o) af[o][t] = acc[o];
  }
  __syncthreads();
  // phase D: final psp+spike -> out
  if (t < OF) {
    float p = 0.f, r = 0.f;
    for (int i = 0; i < TT; ++i) {
      float u = af[t][i];
      p = DSR * p + u;
      float v = p + r;
      float s = (v >= THETA) ? 1.f : 0.f;
      r = DREF * (r - REFAMP * s);
      out[((size_t)n * OF + t) * TT + i] = s;
    }
  }
}

extern "C" void kernel_launch(void* const* d_in, const int* in_sizes, int n_in,
                              void* d_out, int out_size, void* d_ws, size_t ws_size,
                              hipStream_t stream) {
  (void)in_sizes; (void)n_in; (void)out_size; (void)ws_size;
  const float* xt  = (const float*)d_in[0];
  const float* xv  = (const float*)d_in[1];
  const float* Wt  = (const float*)d_in[2];
  const float* Wv1 = (const float*)d_in[3];
  const float* Wv2 = (const float*)d_in[4];
  const float* Wf  = (const float*)d_in[5];
  float* out = (float*)d_out;

  char* ws = (char*)d_ws;
  size_t off = 0;
  auto carve = [&](size_t bytes) {
    char* p = ws + off;
    off += (bytes + 255) & ~(size_t)255;
    return p;
  };
  unsigned short* whi    = (unsigned short*)carve((size_t)O1 * KP * 2);
  unsigned short* wlo    = (unsigned short*)carve((size_t)O1 * KP * 2);
  unsigned short* xbT    = (unsigned short*)carve((size_t)NB * TP * KP * 2);
  float*          a1     = (float*)carve((size_t)O1 * NC * 4);
  unsigned short* sv1    = (unsigned short*)carve((size_t)NB * O1 * TT * 2);
  float*          stact  = (float*)carve((size_t)NB * OT * TT * 4);
  float*          a2     = (float*)carve((size_t)NB * O2 * TT * 4);

  k_splitw<<<dim3((O1 * KP + 255) / 256), dim3(256), 0, stream>>>(Wv1, whi, wlo);
  k_xpose<<<dim3(KP / 64, TP / 64, NB), dim3(256), 0, stream>>>(xv, xbT);
  k_tact<<<dim3(NB * 2), dim3(512), 0, stream>>>(xt, Wt, stact);
  k_gemm<<<dim3(NC / 128, O1 / 128), dim3(256), 0, stream>>>(whi, wlo, xbT, a1);
  k_spk1<<<dim3(64), dim3(256), 0, stream>>>(a1, sv1);
  k_vis2<<<dim3(NB, (TP + 63) / 64), dim3(256), 0, stream>>>(sv1, Wv2, a2);
  k_finish<<<dim3(NB), dim3(512), 0, stream>>>(a2, stact, Wf, out);
}

// Round 3
// 576.379 us; speedup vs baseline: 1.5394x; 1.0835x over previous
//
#include <hip/hip_runtime.h>
#include <stdint.h>

#define DSR   0.90483741803595952f   // exp(-1/10)
#define DREF  0.36787944117144233f   // exp(-1)
#define THETA 10.0f
#define REFAMP 20.0f                 // SCALE_REF * THETA

#define NB 16
#define TT 500
#define TP 512
#define F1 6300
#define KP 6336      // K padded (multiple of 64)
#define O1 1024
#define NC 8192      // NB * TP columns
#define FT 156
#define OT 50
#define O2 10
#define OF 20

typedef __attribute__((ext_vector_type(8))) short    short8;
typedef __attribute__((ext_vector_type(4))) float    f32x4;
typedef __attribute__((ext_vector_type(8))) unsigned short ushort8v;

#define GLL16(g, l) __builtin_amdgcn_global_load_lds( \
    (const __attribute__((address_space(1))) void*)(g), \
    (__attribute__((address_space(3))) void*)(l), 16, 0, 0)

static __device__ __forceinline__ unsigned short f2bf(float x) {
  unsigned u = __float_as_uint(x);
  unsigned r = (u + 0x7FFFu + ((u >> 16) & 1u)) >> 16;   // RNE
  return (unsigned short)r;
}
static __device__ __forceinline__ float bf2f(unsigned short b) {
  return __uint_as_float((unsigned)b << 16);
}

// ---------------- K0a: split Wv1 into bf16 hi/lo, zero-pad K to 6336 --------
__global__ void k_splitw(const float* __restrict__ W, unsigned short* __restrict__ whi,
                         unsigned short* __restrict__ wlo) {
  int idx = blockIdx.x * 256 + threadIdx.x;
  if (idx >= O1 * KP) return;
  int o = idx / KP, f = idx - o * KP;
  float w = (f < F1) ? W[o * F1 + f] : 0.0f;
  unsigned short h = f2bf(w);
  float hf = bf2f(h);
  unsigned short l = f2bf(w - hf);
  whi[idx] = h;
  wlo[idx] = l;
}

// ---------------- K0b: transpose xv (n,f,t) -> xbT[(n*512+t)*6336 + f] bf16 --
__global__ void k_xpose(const float* __restrict__ xv, unsigned short* __restrict__ xbT) {
  __shared__ unsigned short tile[64][68];
  int ft = blockIdx.x, tt = blockIdx.y, n = blockIdx.z;
  int tx = threadIdx.x & 63, ty = threadIdx.x >> 6;  // 64 x 4
  int f0 = ft * 64, t0 = tt * 64;
#pragma unroll
  for (int i = 0; i < 16; ++i) {
    int fr = ty * 16 + i;
    int f = f0 + fr, t = t0 + tx;
    float v = (f < F1 && t < TT) ? xv[((size_t)n * F1 + f) * TT + t] : 0.0f;
    tile[fr][tx] = f2bf(v);
  }
  __syncthreads();
#pragma unroll
  for (int i = 0; i < 16; ++i) {
    int tr = ty * 16 + i;
    xbT[((size_t)n * TP + (t0 + tr)) * KP + (f0 + tx)] = tile[tx][tr];
  }
}

// ---------------- K1: tactile: dense(Wt,xt) -> psp -> spike -> s_tact -------
__global__ void __launch_bounds__(512) k_tact(const float* __restrict__ xt,
                                              const float* __restrict__ Wt,
                                              float* __restrict__ s_tact) {
  __shared__ float at_s[25 * TP];
  int n = blockIdx.x >> 1, half = blockIdx.x & 1;
  int t = threadIdx.x;
  if (t < TT) {
    float acc[25];
#pragma unroll
    for (int o = 0; o < 25; ++o) acc[o] = 0.f;
    for (int f = 0; f < FT; ++f) {
      float x = xt[((size_t)n * FT + f) * TT + t];
      if (x != 0.f) {
#pragma unroll
        for (int o = 0; o < 25; ++o)
          acc[o] += Wt[(half * 25 + o) * FT + f] * x;
      }
    }
#pragma unroll
    for (int o = 0; o < 25; ++o) at_s[o * TP + t] = acc[o];
  }
  __syncthreads();
  if (t < 25) {
    float p = 0.f, r = 0.f;
    int ob = half * 25 + t;
    for (int i = 0; i < TT; ++i) {
      float u = at_s[t * TP + i];
      p = DSR * p + u;
      float v = p + r;
      float s = (v >= THETA) ? 1.0f : 0.0f;
      r = DREF * (r - REFAMP * s);
      s_tact[((size_t)n * OT + ob) * TT + i] = s;
    }
  }
}

// ---------------- K2: GEMM  C(1024x8192) = [Whi+Wlo](1024xK) * xbT^T --------
// 128x128 tile, BK=64, 256 thr, global_load_lds(16B), fused hi/lo.
// Granule(16B) swizzle: phys m at row r holds logical granule m ^ (r&7);
// applied on the GLOBAL source address, LDS dest linear (rule #21).
__global__ void __launch_bounds__(256) k_gemm(const unsigned short* __restrict__ whi,
                                              const unsigned short* __restrict__ wlo,
                                              const unsigned short* __restrict__ BT,
                                              float* __restrict__ C) {
  __shared__ unsigned short Ah[128 * 64];
  __shared__ unsigned short Al[128 * 64];
  __shared__ unsigned short Bs[128 * 64];
  int tid = threadIdx.x;
  int gx = blockIdx.x, gy = blockIdx.y;
  int wave = tid >> 6, lane = tid & 63;
  int wr = wave >> 1, wc = wave & 1;
  int lr = lane & 15, lg = lane >> 4;

  f32x4 acc[4][4];
#pragma unroll
  for (int m = 0; m < 4; ++m)
#pragma unroll
    for (int nn = 0; nn < 4; ++nn) acc[m][nn] = (f32x4)0.f;

  // staging round j: phys granule p = j*256+tid; row = j*32 + (tid>>3),
  // phys-within-row m = tid&7, src granule s = m ^ (row&7) = (tid&7)^((tid>>3)&7)
  int srow = tid >> 3;
  int sgr  = (tid & 7) ^ (srow & 7);
  size_t ga[4], gb[4];
#pragma unroll
  for (int j = 0; j < 4; ++j) {
    ga[j] = (size_t)(gy * 128 + j * 32 + srow) * KP + sgr * 8;
    gb[j] = (size_t)(gx * 128 + j * 32 + srow) * KP + sgr * 8;
  }
  unsigned ldsb = (unsigned)(wave * 1024);   // + j*4096

  // fragment LDS element offsets (row ra, k-sub kk, granule lg)
  int offA[4][2], offB[4][2];
#pragma unroll
  for (int m = 0; m < 4; ++m) {
    int ra = wr * 64 + m * 16 + lr;
#pragma unroll
    for (int kk = 0; kk < 2; ++kk)
      offA[m][kk] = ra * 64 + (((kk * 4 + lg) ^ (ra & 7)) * 8);
  }
#pragma unroll
  for (int nn = 0; nn < 4; ++nn) {
    int rb = wc * 64 + nn * 16 + lr;
#pragma unroll
    for (int kk = 0; kk < 2; ++kk)
      offB[nn][kk] = rb * 64 + (((kk * 4 + lg) ^ (rb & 7)) * 8);
  }

  for (int ks = 0; ks < KP / 64; ++ks) {
    size_t ko = (size_t)ks * 64;
#pragma unroll
    for (int j = 0; j < 4; ++j) {
      GLL16(whi + ga[j] + ko, (char*)Ah + j * 4096 + ldsb);
      GLL16(wlo + ga[j] + ko, (char*)Al + j * 4096 + ldsb);
      GLL16(BT  + gb[j] + ko, (char*)Bs + j * 4096 + ldsb);
    }
    __syncthreads();
#pragma unroll
    for (int kk = 0; kk < 2; ++kk) {
      short8 ah[4], al[4], bv[4];
#pragma unroll
      for (int m = 0; m < 4; ++m) {
        ah[m] = *(const short8*)(Ah + offA[m][kk]);
        al[m] = *(const short8*)(Al + offA[m][kk]);
      }
#pragma unroll
      for (int nn = 0; nn < 4; ++nn)
        bv[nn] = *(const short8*)(Bs + offB[nn][kk]);
#pragma unroll
      for (int m = 0; m < 4; ++m)
#pragma unroll
        for (int nn = 0; nn < 4; ++nn) {
          acc[m][nn] = __builtin_amdgcn_mfma_f32_16x16x32_bf16(ah[m], bv[nn], acc[m][nn], 0, 0, 0);
          acc[m][nn] = __builtin_amdgcn_mfma_f32_16x16x32_bf16(al[m], bv[nn], acc[m][nn], 0, 0, 0);
        }
    }
    __syncthreads();
  }
#pragma unroll
  for (int m = 0; m < 4; ++m)
#pragma unroll
    for (int nn = 0; nn < 4; ++nn) {
      int o = gy * 128 + wr * 64 + m * 16 + lg * 4;
      int c = gx * 128 + wc * 64 + nn * 16 + lr;
#pragma unroll
      for (int reg = 0; reg < 4; ++reg)
        C[(size_t)(o + reg) * NC + c] = acc[m][nn][reg];
    }
}

// ---------------- K3: psp+spike -> sv1, LDS-staged & coalesced --------------
// grid (16 o-groups, 16 n) x 256 thr; sv1 rows padded to TP.
__global__ void __launch_bounds__(256) k_spk1(const float* __restrict__ C,
                                              unsigned short* __restrict__ sv1) {
  __shared__ float tile[64][129];            // 33 KB
  __shared__ unsigned short stile[64][136];  // 17.4 KB
  int og = blockIdx.x, n = blockIdx.y;
  int tid = threadIdx.x;
  float p = 0.f, r = 0.f;
  for (int tc = 0; tc < 4; ++tc) {
    // coop load 64 rows x 128 floats (f32x4, coalesced along t)
#pragma unroll
    for (int i = 0; i < 8; ++i) {
      int idx = i * 256 + tid;
      int row = idx >> 5, c4 = idx & 31;
      f32x4 v = *(const f32x4*)(C + (size_t)(og * 64 + row) * NC + n * TP + tc * 128 + c4 * 4);
      *(f32x4*)&tile[row][c4 * 4] = v;
    }
    __syncthreads();
    if (tid < 64) {
      float pp = p, rr = r;
      for (int i = 0; i < 128; ++i) {
        float u = tile[tid][i];
        pp = DSR * pp + u;
        float v = pp + rr;
        bool s = (v >= THETA);
        rr = DREF * (rr - (s ? REFAMP : 0.f));
        stile[tid][i] = s ? (unsigned short)0x3F80 : (unsigned short)0;
      }
      p = pp; r = rr;
    }
    __syncthreads();
    // coop store 64 rows x 128 ushort (ushort8, coalesced)
#pragma unroll
    for (int i = 0; i < 4; ++i) {
      int idx = i * 256 + tid;
      int row = idx >> 4, c8 = idx & 15;
      ushort8v v = *(const ushort8v*)&stile[row][c8 * 8];
      *(ushort8v*)(sv1 + ((size_t)n * O1 + og * 64 + row) * TP + tc * 128 + c8 * 8) = v;
    }
    __syncthreads();
  }
}

// ---------------- K4: a2[n][o][t] = Wv2 @ sv1 (parallel, coalesced) ---------
__global__ void __launch_bounds__(256) k_vis2(const unsigned short* __restrict__ sv1,
                                              const float* __restrict__ Wv2,
                                              float* __restrict__ a2) {
  __shared__ float w2[O2 * O1];        // 40 KB
  __shared__ float red[3][O2][64];     // 7.5 KB
  int n = blockIdx.x, t0 = blockIdx.y * 64;
  int tid = threadIdx.x, lane = tid & 63, w = tid >> 6;
  for (int i = tid; i < O2 * O1; i += 256) w2[i] = Wv2[i];
  __syncthreads();
  int t = t0 + lane;
  bool tv = t < TT;
  const unsigned short* sp = sv1 + ((size_t)n * O1 + w * 256) * TP + (tv ? t : 0);
  float acc[O2];
#pragma unroll
  for (int o = 0; o < O2; ++o) acc[o] = 0.f;
  for (int f = 0; f < 256; ++f) {
    float s = tv ? bf2f(sp[(size_t)f * TP]) : 0.f;
    int fg = w * 256 + f;
#pragma unroll
    for (int o = 0; o < O2; ++o) acc[o] = fmaf(w2[o * O1 + fg], s, acc[o]);
  }
  if (w) {
#pragma unroll
    for (int o = 0; o < O2; ++o) red[w - 1][o][lane] = acc[o];
  }
  __syncthreads();
  if (w == 0 && tv) {
#pragma unroll
    for (int o = 0; o < O2; ++o) {
      float v = acc[o] + red[0][o][lane] + red[1][o][lane] + red[2][o][lane];
      a2[((size_t)n * O2 + o) * TP + t] = v;
    }
  }
}

// ---------------- K5: head: psp+spike(a2) -> concat -> Wf -> psp+spike ------
__global__ void __launch_bounds__(512) k_finish(const float* __restrict__ a2,
                                                const float* __restrict__ s_tact,
                                                const float* __restrict__ Wf,
                                                float* __restrict__ out) {
  __shared__ float u2[O2 * 516];   // 20.6 KB (staged a2, then spikes in place)
  __shared__ float af[OF * 516];   // 41.3 KB
  int n = blockIdx.x, t = threadIdx.x;
  // stage a2 (coalesced; rows contiguous since stride TP)
  for (int i = t; i < O2 * TP; i += 512) {
    int o = i >> 9, tt = i & 511;
    u2[o * 516 + tt] = a2[(size_t)n * O2 * TP + i];
  }
  __syncthreads();
  // vis psp+spike (serial, LDS only)
  if (t < O2) {
    float p = 0.f, r = 0.f;
    for (int i = 0; i < TT; ++i) {
      float u = u2[t * 516 + i];
      p = DSR * p + u;
      float v = p + r;
      float s = (v >= THETA) ? 1.f : 0.f;
      r = DREF * (r - REFAMP * s);
      u2[t * 516 + i] = s;
    }
  }
  __syncthreads();
  // af = Wf @ [s_tact ; s_vis]
  if (t < TT) {
    float acc[OF];
#pragma unroll
    for (int o = 0; o < OF; ++o) acc[o] = 0.f;
    for (int f = 0; f < OT; ++f) {
      float s = s_tact[((size_t)n * OT + f) * TT + t];
      if (s != 0.f) {
#pragma unroll
        for (int o = 0; o < OF; ++o)
          acc[o] += Wf[o * 60 + f];
      }
    }
#pragma unroll
    for (int f = 0; f < O2; ++f) {
      float s = u2[f * 516 + t];
      if (s != 0.f) {
#pragma unroll
        for (int o = 0; o < OF; ++o)
          acc[o] += Wf[o * 60 + OT + f];
      }
    }
#pragma unroll
    for (int o = 0; o < OF; ++o) af[o * 516 + t] = acc[o];
  }
  __syncthreads();
  // final psp+spike -> out
  if (t < OF) {
    float p = 0.f, r = 0.f;
    for (int i = 0; i < TT; ++i) {
      float u = af[t * 516 + i];
      p = DSR * p + u;
      float v = p + r;
      float s = (v >= THETA) ? 1.f : 0.f;
      r = DREF * (r - REFAMP * s);
      out[((size_t)n * OF + t) * TT + i] = s;
    }
  }
}

extern "C" void kernel_launch(void* const* d_in, const int* in_sizes, int n_in,
                              void* d_out, int out_size, void* d_ws, size_t ws_size,
                              hipStream_t stream) {
  (void)in_sizes; (void)n_in; (void)out_size; (void)ws_size;
  const float* xt  = (const float*)d_in[0];
  const float* xv  = (const float*)d_in[1];
  const float* Wt  = (const float*)d_in[2];
  const float* Wv1 = (const float*)d_in[3];
  const float* Wv2 = (const float*)d_in[4];
  const float* Wf  = (const float*)d_in[5];
  float* out = (float*)d_out;

  char* ws = (char*)d_ws;
  size_t off = 0;
  auto carve = [&](size_t bytes) {
    char* p = ws + off;
    off += (bytes + 255) & ~(size_t)255;
    return p;
  };
  unsigned short* whi    = (unsigned short*)carve((size_t)O1 * KP * 2);
  unsigned short* wlo    = (unsigned short*)carve((size_t)O1 * KP * 2);
  unsigned short* xbT    = (unsigned short*)carve((size_t)NB * TP * KP * 2);
  float*          a1     = (float*)carve((size_t)O1 * NC * 4);
  unsigned short* sv1    = (unsigned short*)carve((size_t)NB * O1 * TP * 2);
  float*          stact  = (float*)carve((size_t)NB * OT * TT * 4);
  float*          a2     = (float*)carve((size_t)NB * O2 * TP * 4);

  k_splitw<<<dim3((O1 * KP + 255) / 256), dim3(256), 0, stream>>>(Wv1, whi, wlo);
  k_xpose<<<dim3(KP / 64, TP / 64, NB), dim3(256), 0, stream>>>(xv, xbT);
  k_tact<<<dim3(NB * 2), dim3(512), 0, stream>>>(xt, Wt, stact);
  k_gemm<<<dim3(NC / 128, O1 / 128), dim3(256), 0, stream>>>(whi, wlo, xbT, a1);
  k_spk1<<<dim3(16, NB), dim3(256), 0, stream>>>(a1, sv1);
  k_vis2<<<dim3(NB, (TP + 63) / 64), dim3(256), 0, stream>>>(sv1, Wv2, a2);
  k_finish<<<dim3(NB), dim3(512), 0, stream>>>(a2, stact, Wf, out);
}

// Round 4
// 543.124 us; speedup vs baseline: 1.6337x; 1.0612x over previous
//
#include <hip/hip_runtime.h>
#include <stdint.h>

#define DSR   0.90483741803595952f   // exp(-1/10)
#define DREF  0.36787944117144233f   // exp(-1)
#define THETA 10.0f
#define REFAMP 20.0f                 // SCALE_REF * THETA

#define NB 16
#define TT 500
#define TP 512
#define F1 6300
#define KP 6336      // K padded (multiple of 64)
#define NK 99        // KP/64
#define O1 1024
#define NC 8192      // NB * TP columns
#define FT 156
#define OT 50
#define O2 10
#define OF 20

typedef __attribute__((ext_vector_type(8))) short    short8;
typedef __attribute__((ext_vector_type(4))) float    f32x4;

#define GLL16(g, l) __builtin_amdgcn_global_load_lds( \
    (const __attribute__((address_space(1))) void*)(g), \
    (__attribute__((address_space(3))) void*)(l), 16, 0, 0)

static __device__ __forceinline__ unsigned short f2bf(float x) {
  unsigned u = __float_as_uint(x);
  unsigned r = (u + 0x7FFFu + ((u >> 16) & 1u)) >> 16;   // RNE
  return (unsigned short)r;
}
static __device__ __forceinline__ float bf2f(unsigned short b) {
  return __uint_as_float((unsigned)b << 16);
}

// ---------------- K0a: split Wv1 into bf16 hi/lo, zero-pad K to 6336 --------
__global__ void k_splitw(const float* __restrict__ W, unsigned short* __restrict__ whi,
                         unsigned short* __restrict__ wlo) {
  int idx = blockIdx.x * 256 + threadIdx.x;
  if (idx >= O1 * KP) return;
  int o = idx / KP, f = idx - o * KP;
  float w = (f < F1) ? W[o * F1 + f] : 0.0f;
  unsigned short h = f2bf(w);
  float hf = bf2f(h);
  unsigned short l = f2bf(w - hf);
  whi[idx] = h;
  wlo[idx] = l;
}

// ---------------- K0b: transpose xv (n,f,t) -> xbT[(n*512+t)*6336 + f] bf16 --
__global__ void k_xpose(const float* __restrict__ xv, unsigned short* __restrict__ xbT) {
  __shared__ unsigned short tile[64][68];
  int ft = blockIdx.x, tt = blockIdx.y, n = blockIdx.z;
  int tx = threadIdx.x & 63, ty = threadIdx.x >> 6;  // 64 x 4
  int f0 = ft * 64, t0 = tt * 64;
#pragma unroll
  for (int i = 0; i < 16; ++i) {
    int fr = ty * 16 + i;
    int f = f0 + fr, t = t0 + tx;
    float v = (f < F1 && t < TT) ? xv[((size_t)n * F1 + f) * TT + t] : 0.0f;
    tile[fr][tx] = f2bf(v);
  }
  __syncthreads();
#pragma unroll
  for (int i = 0; i < 16; ++i) {
    int tr = ty * 16 + i;
    xbT[((size_t)n * TP + (t0 + tr)) * KP + (f0 + tx)] = tile[tx][tr];
  }
}

// ---------------- K1: tactile: dense(Wt,xt) -> psp -> spike -> s_tact -------
// col-major LDS [t][o] (pad 26): conflict-free serial scan, branchless matmul.
__global__ void __launch_bounds__(512) k_tact(const float* __restrict__ xt,
                                              const float* __restrict__ Wt,
                                              float* __restrict__ s_tact) {
  __shared__ float atv[TP * 26];   // [t][o] 53 KB
  int n = blockIdx.x >> 1, half = blockIdx.x & 1;
  int t = threadIdx.x;
  if (t < TT) {
    float acc[25];
#pragma unroll
    for (int o = 0; o < 25; ++o) acc[o] = 0.f;
    for (int f = 0; f < FT; ++f) {
      float x = xt[((size_t)n * FT + f) * TT + t];
#pragma unroll
      for (int o = 0; o < 25; ++o)
        acc[o] = fmaf(Wt[(half * 25 + o) * FT + f], x, acc[o]);
    }
#pragma unroll
    for (int o = 0; o < 25; ++o) atv[t * 26 + o] = acc[o];
  }
  __syncthreads();
  if (t < 25) {
    float p = 0.f, r = 0.f;
    int ob = half * 25 + t;
    float* op = s_tact + ((size_t)n * OT + ob) * TT;
#pragma unroll 4
    for (int i = 0; i < TT; ++i) {
      float u = atv[i * 26 + t];
      p = DSR * p + u;
      float v = p + r;
      bool s = (v >= THETA);
      r = DREF * (r - (s ? REFAMP : 0.f));
      op[i] = s ? 1.f : 0.f;
    }
  }
}

// ---------------- K2: GEMM  C(1024x8192) = [Whi+Wlo](1024xK) * xbT^T --------
// 128x256 tile, BK=64, 512 thr, double-buffered LDS (128KB, 1 block/CU),
// global_load_lds(16B) staged BEFORE compute, one barrier per K-step.
// Granule(16B) XOR swizzle applied on the GLOBAL source, LDS dest linear.
__global__ void __launch_bounds__(512, 2) k_gemm(const unsigned short* __restrict__ whi,
                                                 const unsigned short* __restrict__ wlo,
                                                 const unsigned short* __restrict__ BT,
                                                 float* __restrict__ C) {
  __shared__ unsigned short Ah[2][128 * 64];   // 16 KB x2
  __shared__ unsigned short Al[2][128 * 64];   // 16 KB x2
  __shared__ unsigned short Bs[2][256 * 64];   // 32 KB x2
  int tid = threadIdx.x;
  int gx = blockIdx.x, gy = blockIdx.y;
  int wave = tid >> 6, lane = tid & 63;
  int wr = wave >> 2, wc = wave & 3;           // 2 x 4 wave grid
  int lr = lane & 15, lg = lane >> 4;

  f32x4 acc[4][4];
#pragma unroll
  for (int m = 0; m < 4; ++m)
#pragma unroll
    for (int nn = 0; nn < 4; ++nn) acc[m][nn] = (f32x4)0.f;

  // staging: granule p = j*512 + tid; row = p>>3 = j*64 + (tid>>3); phys m = tid&7
  // source granule = m ^ (row&7)  (row&7 independent of j since j*64 % 8 == 0)
  int row0 = tid >> 3;
  int src  = (tid & 7) ^ (row0 & 7);
  size_t gaoff[2], gboff[4];
#pragma unroll
  for (int j = 0; j < 2; ++j)
    gaoff[j] = (size_t)(gy * 128 + j * 64 + row0) * KP + src * 8;
#pragma unroll
  for (int j = 0; j < 4; ++j)
    gboff[j] = (size_t)(gx * 256 + j * 64 + row0) * KP + src * 8;
  unsigned ldso = (unsigned)tid * 16u;         // + j*8192 bytes

  // fragment physical granule indices
  int offA[4][2], offB[4][2];
#pragma unroll
  for (int m = 0; m < 4; ++m) {
    int ra = wr * 64 + m * 16 + lr;
#pragma unroll
    for (int kk = 0; kk < 2; ++kk)
      offA[m][kk] = ra * 8 + ((kk * 4 + lg) ^ (ra & 7));
  }
#pragma unroll
  for (int nn = 0; nn < 4; ++nn) {
    int rb = wc * 64 + nn * 16 + lr;
#pragma unroll
    for (int kk = 0; kk < 2; ++kk)
      offB[nn][kk] = rb * 8 + ((kk * 4 + lg) ^ (rb & 7));
  }

  // prologue: stage K-step 0 into buffer 0
  {
    size_t ko = 0;
#pragma unroll
    for (int j = 0; j < 2; ++j) {
      GLL16(whi + gaoff[j] + ko, (char*)&Ah[0][0] + j * 8192 + ldso);
      GLL16(wlo + gaoff[j] + ko, (char*)&Al[0][0] + j * 8192 + ldso);
    }
#pragma unroll
    for (int j = 0; j < 4; ++j)
      GLL16(BT + gboff[j] + ko, (char*)&Bs[0][0] + j * 8192 + ldso);
  }
  __syncthreads();

  for (int ks = 0; ks < NK; ++ks) {
    int cur = ks & 1;
    if (ks + 1 < NK) {                         // stage next tile first
      size_t ko = (size_t)(ks + 1) * 64;
      int nxt = cur ^ 1;
#pragma unroll
      for (int j = 0; j < 2; ++j) {
        GLL16(whi + gaoff[j] + ko, (char*)&Ah[nxt][0] + j * 8192 + ldso);
        GLL16(wlo + gaoff[j] + ko, (char*)&Al[nxt][0] + j * 8192 + ldso);
      }
#pragma unroll
      for (int j = 0; j < 4; ++j)
        GLL16(BT + gboff[j] + ko, (char*)&Bs[nxt][0] + j * 8192 + ldso);
    }
#pragma unroll
    for (int kk = 0; kk < 2; ++kk) {
      short8 ah[4], al[4], bv[4];
#pragma unroll
      for (int m = 0; m < 4; ++m) {
        ah[m] = *(const short8*)(&Ah[cur][0] + offA[m][kk] * 8);
        al[m] = *(const short8*)(&Al[cur][0] + offA[m][kk] * 8);
      }
#pragma unroll
      for (int nn = 0; nn < 4; ++nn)
        bv[nn] = *(const short8*)(&Bs[cur][0] + offB[nn][kk] * 8);
      __builtin_amdgcn_s_setprio(1);
#pragma unroll
      for (int m = 0; m < 4; ++m)
#pragma unroll
        for (int nn = 0; nn < 4; ++nn) {
          acc[m][nn] = __builtin_amdgcn_mfma_f32_16x16x32_bf16(ah[m], bv[nn], acc[m][nn], 0, 0, 0);
          acc[m][nn] = __builtin_amdgcn_mfma_f32_16x16x32_bf16(al[m], bv[nn], acc[m][nn], 0, 0, 0);
        }
      __builtin_amdgcn_s_setprio(0);
    }
    __syncthreads();   // implicit vmcnt(0)+lgkmcnt(0): next buffer staged, cur reads done
  }

#pragma unroll
  for (int m = 0; m < 4; ++m)
#pragma unroll
    for (int nn = 0; nn < 4; ++nn) {
      int o = gy * 128 + wr * 64 + m * 16 + lg * 4;
      int c = gx * 256 + wc * 64 + nn * 16 + lr;
#pragma unroll
      for (int reg = 0; reg < 4; ++reg)
        C[(size_t)(o + reg) * NC + c] = acc[m][nn][reg];
    }
}

// ---------------- K3: psp+spike -> sv1 (col-major LDS, packed spike store) --
__global__ void __launch_bounds__(256) k_spk1(const float* __restrict__ C,
                                              unsigned int* __restrict__ sv1u) {
  __shared__ float tile[128 * 65];        // [t_local][row]  33.3 KB
  __shared__ unsigned int spk[64 * 65];   // [t_pair][row]   16.6 KB
  int og = blockIdx.x, n = blockIdx.y;
  int tid = threadIdx.x;
  float p = 0.f, r = 0.f;
  for (int tc = 0; tc < 4; ++tc) {
    // coop load 64 rows x 128 t (f32x4), scatter to col-major LDS
#pragma unroll
    for (int i = 0; i < 8; ++i) {
      int idx = i * 256 + tid;
      int row = idx >> 5, c4 = idx & 31;
      f32x4 v = *(const f32x4*)(C + (size_t)(og * 64 + row) * NC + n * TP + tc * 128 + c4 * 4);
#pragma unroll
      for (int j = 0; j < 4; ++j) tile[(c4 * 4 + j) * 65 + row] = v[j];
    }
    __syncthreads();
    if (tid < 64) {
      float pp = p, rr = r;
#pragma unroll 8
      for (int i2 = 0; i2 < 64; ++i2) {
        float u0 = tile[(i2 * 2) * 65 + tid];
        float u1 = tile[(i2 * 2 + 1) * 65 + tid];
        pp = DSR * pp + u0;
        float v0 = pp + rr;
        bool s0 = (v0 >= THETA);
        rr = DREF * (rr - (s0 ? REFAMP : 0.f));
        pp = DSR * pp + u1;
        float v1 = pp + rr;
        bool s1 = (v1 >= THETA);
        rr = DREF * (rr - (s1 ? REFAMP : 0.f));
        spk[i2 * 65 + tid] = (s0 ? 0x3F80u : 0u) | (s1 ? 0x3F800000u : 0u);
      }
      p = pp; r = rr;
    }
    __syncthreads();
    // coop store 64 rows x 64 uints (coalesced)
#pragma unroll
    for (int i = 0; i < 16; ++i) {
      int idx = i * 256 + tid;
      int row = idx >> 6, c = idx & 63;
      sv1u[((size_t)n * O1 + og * 64 + row) * (TP / 2) + tc * 64 + c] = spk[c * 65 + row];
    }
    __syncthreads();
  }
}

// ---------------- K4: a2[n][o][t] = Wv2 @ sv1 (parallel, coalesced) ---------
__global__ void __launch_bounds__(256) k_vis2(const unsigned short* __restrict__ sv1,
                                              const float* __restrict__ Wv2,
                                              float* __restrict__ a2) {
  __shared__ float w2[O2 * O1];        // 40 KB
  __shared__ float red[3][O2][64];     // 7.5 KB
  int n = blockIdx.x, t0 = blockIdx.y * 64;
  int tid = threadIdx.x, lane = tid & 63, w = tid >> 6;
  for (int i = tid; i < O2 * O1; i += 256) w2[i] = Wv2[i];
  __syncthreads();
  int t = t0 + lane;
  bool tv = t < TT;
  const unsigned short* sp = sv1 + ((size_t)n * O1 + w * 256) * TP + (tv ? t : 0);
  float acc[O2];
#pragma unroll
  for (int o = 0; o < O2; ++o) acc[o] = 0.f;
  for (int f = 0; f < 256; ++f) {
    float s = tv ? bf2f(sp[(size_t)f * TP]) : 0.f;
    int fg = w * 256 + f;
#pragma unroll
    for (int o = 0; o < O2; ++o) acc[o] = fmaf(w2[o * O1 + fg], s, acc[o]);
  }
  if (w) {
#pragma unroll
    for (int o = 0; o < O2; ++o) red[w - 1][o][lane] = acc[o];
  }
  __syncthreads();
  if (w == 0 && tv) {
#pragma unroll
    for (int o = 0; o < O2; ++o) {
      float v = acc[o] + red[0][o][lane] + red[1][o][lane] + red[2][o][lane];
      a2[((size_t)n * O2 + o) * TP + t] = v;
    }
  }
}

// ---------------- K5: head: psp+spike(a2) -> concat -> Wf -> psp+spike ------
// col-major LDS: u2[t][12], af[t][21] — conflict-free serial scans.
__global__ void __launch_bounds__(512) k_finish(const float* __restrict__ a2,
                                                const float* __restrict__ s_tact,
                                                const float* __restrict__ Wf,
                                                float* __restrict__ out) {
  __shared__ float u2[TP * 12];   // 24.6 KB
  __shared__ float af[TP * 21];   // 43 KB
  int n = blockIdx.x, t = threadIdx.x;
  // stage a2 -> col-major
#pragma unroll
  for (int j = 0; j < O2; ++j)
    u2[t * 12 + j] = a2[((size_t)n * O2 + j) * TP + t];
  __syncthreads();
  // vis psp+spike (serial, conflict-free)
  if (t < O2) {
    float p = 0.f, r = 0.f;
#pragma unroll 4
    for (int i = 0; i < TT; ++i) {
      float u = u2[i * 12 + t];
      p = DSR * p + u;
      float v = p + r;
      bool s = (v >= THETA);
      r = DREF * (r - (s ? REFAMP : 0.f));
      u2[i * 12 + t] = s ? 1.f : 0.f;
    }
  }
  __syncthreads();
  // af = Wf @ [s_tact ; s_vis]  (branchless)
  if (t < TT) {
    float acc[OF];
#pragma unroll
    for (int o = 0; o < OF; ++o) acc[o] = 0.f;
    for (int f = 0; f < OT; ++f) {
      float s = s_tact[((size_t)n * OT + f) * TT + t];
#pragma unroll
      for (int o = 0; o < OF; ++o) acc[o] = fmaf(Wf[o * 60 + f], s, acc[o]);
    }
#pragma unroll
    for (int f = 0; f < O2; ++f) {
      float s = u2[t * 12 + f];
#pragma unroll
      for (int o = 0; o < OF; ++o) acc[o] = fmaf(Wf[o * 60 + OT + f], s, acc[o]);
    }
#pragma unroll
    for (int o = 0; o < OF; ++o) af[t * 21 + o] = acc[o];
  }
  __syncthreads();
  // final psp+spike -> out
  if (t < OF) {
    float p = 0.f, r = 0.f;
    float* op = out + ((size_t)n * OF + t) * TT;
#pragma unroll 4
    for (int i = 0; i < TT; ++i) {
      float u = af[i * 21 + t];
      p = DSR * p + u;
      float v = p + r;
      bool s = (v >= THETA);
      r = DREF * (r - (s ? REFAMP : 0.f));
      op[i] = s ? 1.f : 0.f;
    }
  }
}

extern "C" void kernel_launch(void* const* d_in, const int* in_sizes, int n_in,
                              void* d_out, int out_size, void* d_ws, size_t ws_size,
                              hipStream_t stream) {
  (void)in_sizes; (void)n_in; (void)out_size; (void)ws_size;
  const float* xt  = (const float*)d_in[0];
  const float* xv  = (const float*)d_in[1];
  const float* Wt  = (const float*)d_in[2];
  const float* Wv1 = (const float*)d_in[3];
  const float* Wv2 = (const float*)d_in[4];
  const float* Wf  = (const float*)d_in[5];
  float* out = (float*)d_out;

  char* ws = (char*)d_ws;
  size_t off = 0;
  auto carve = [&](size_t bytes) {
    char* p = ws + off;
    off += (bytes + 255) & ~(size_t)255;
    return p;
  };
  unsigned short* whi    = (unsigned short*)carve((size_t)O1 * KP * 2);
  unsigned short* wlo    = (unsigned short*)carve((size_t)O1 * KP * 2);
  unsigned short* xbT    = (unsigned short*)carve((size_t)NB * TP * KP * 2);
  float*          a1     = (float*)carve((size_t)O1 * NC * 4);
  unsigned short* sv1    = (unsigned short*)carve((size_t)NB * O1 * TP * 2);
  float*          stact  = (float*)carve((size_t)NB * OT * TT * 4);
  float*          a2     = (float*)carve((size_t)NB * O2 * TP * 4);

  k_splitw<<<dim3((O1 * KP + 255) / 256), dim3(256), 0, stream>>>(Wv1, whi, wlo);
  k_xpose<<<dim3(KP / 64, TP / 64, NB), dim3(256), 0, stream>>>(xv, xbT);
  k_tact<<<dim3(NB * 2), dim3(512), 0, stream>>>(xt, Wt, stact);
  k_gemm<<<dim3(NC / 256, O1 / 128), dim3(512), 0, stream>>>(whi, wlo, xbT, a1);
  k_spk1<<<dim3(16, NB), dim3(256), 0, stream>>>(a1, (unsigned int*)sv1);
  k_vis2<<<dim3(NB, (TP + 63) / 64), dim3(256), 0, stream>>>(sv1, Wv2, a2);
  k_finish<<<dim3(NB), dim3(512), 0, stream>>>(a2, stact, Wf, out);
}

// Round 5
// 426.683 us; speedup vs baseline: 2.0795x; 1.2729x over previous
//
#include <hip/hip_runtime.h>
#include <stdint.h>

#define DSR   0.90483741803595952f   // exp(-1/10)
#define DREF  0.36787944117144233f   // exp(-1)
#define THETA 10.0f
#define REFAMP 20.0f                 // SCALE_REF * THETA

#define NB 16
#define TT 500
#define TP 512
#define F1 6300
#define KP 6336      // K padded (multiple of 64)
#define NK 99        // KP/64
#define O1 1024
#define NC 8192      // NB * TP columns
#define FT 156
#define OT 50
#define O2 10
#define OF 20

typedef __attribute__((ext_vector_type(4))) float f32x4;
typedef __attribute__((ext_vector_type(4))) int   i32x4;

#define GLL16(g, l) __builtin_amdgcn_global_load_lds( \
    (const __attribute__((address_space(1))) void*)(g), \
    (__attribute__((address_space(3))) void*)(l), 16, 0, 0)

// ---------------- K0a: Wv1 -> 3 signed base-64 int8 digit planes ------------
// w ~= (l0 + 64*l1 + 4096*l2) * 2^-17, digits in [-32,31]
__global__ void k_split3(const float* __restrict__ W, char* __restrict__ L0,
                         char* __restrict__ L1, char* __restrict__ L2) {
  int idx = blockIdx.x * 256 + threadIdx.x;
  if (idx >= O1 * KP) return;
  int o = idx / KP, f = idx - o * KP;
  float w = (f < F1) ? W[o * F1 + f] : 0.0f;
  int Wq = (int)lrintf(w * 131072.0f);       // 2^17
  int l0 = ((Wq + 32) & 63) - 32;  int W1 = (Wq - l0) >> 6;
  int l1 = ((W1 + 32) & 63) - 32;  int l2 = (W1 - l1) >> 6;
  L0[idx] = (char)l0;
  L1[idx] = (char)l1;
  L2[idx] = (char)l2;
}

// ---------------- K0b: transpose xv (n,f,t) -> xbT[(n*512+t)*6336+f] int8 ---
__global__ void k_xpose(const float* __restrict__ xv, char* __restrict__ xbT) {
  __shared__ char tile[64][68];
  int ft = blockIdx.x, tt = blockIdx.y, n = blockIdx.z;
  int tx = threadIdx.x & 63, ty = threadIdx.x >> 6;  // 64 x 4
  int f0 = ft * 64, t0 = tt * 64;
#pragma unroll
  for (int i = 0; i < 16; ++i) {
    int fr = ty * 16 + i;
    int f = f0 + fr, t = t0 + tx;
    float v = (f < F1 && t < TT) ? xv[((size_t)n * F1 + f) * TT + t] : 0.0f;
    tile[fr][tx] = (v != 0.0f) ? (char)1 : (char)0;
  }
  __syncthreads();
#pragma unroll
  for (int i = 0; i < 16; ++i) {
    int tr = ty * 16 + i;
    xbT[((size_t)n * TP + (t0 + tr)) * KP + (f0 + tx)] = tile[tx][tr];
  }
}

// ---------------- K1: tactile: dense(Wt,xt) -> psp -> spike -> s_tact -------
__global__ void __launch_bounds__(512) k_tact(const float* __restrict__ xt,
                                              const float* __restrict__ Wt,
                                              float* __restrict__ s_tact) {
  __shared__ float atv[TP * 26];   // [t][o]
  int n = blockIdx.x >> 1, half = blockIdx.x & 1;
  int t = threadIdx.x;
  if (t < TT) {
    float acc[25];
#pragma unroll
    for (int o = 0; o < 25; ++o) acc[o] = 0.f;
    for (int f = 0; f < FT; ++f) {
      float x = xt[((size_t)n * FT + f) * TT + t];
#pragma unroll
      for (int o = 0; o < 25; ++o)
        acc[o] = fmaf(Wt[(half * 25 + o) * FT + f], x, acc[o]);
    }
#pragma unroll
    for (int o = 0; o < 25; ++o) atv[t * 26 + o] = acc[o];
  }
  __syncthreads();
  if (t < 25) {
    float p = 0.f, r = 0.f;
    float* op = s_tact + ((size_t)n * OT + half * 25 + t) * TT;
    for (int i = 0; i < TT; i += 10) {     // 50 x 10 batched reads
      float u[10];
#pragma unroll
      for (int j = 0; j < 10; ++j) u[j] = atv[(i + j) * 26 + t];
#pragma unroll
      for (int j = 0; j < 10; ++j) {
        p = DSR * p + u[j];
        float v = p + r;
        bool s = (v >= THETA);
        r = DREF * (r - (s ? REFAMP : 0.f));
        op[i + j] = s ? 1.f : 0.f;
      }
    }
  }
}

// ---------------- K2: GEMM  C = W * xbT^T via i8 MFMA, 3 digit planes -------
// 128x128 tile, BK=64, 256 thr, dbuf LDS 64KB -> 2 blocks/CU.
// acc_A = S0 + 64*S1 (B and B<<6 into same acc); acc_2 = S2.
// 16B-granule XOR swizzle swz4(row)=(row^(row>>2))&3 on GLOBAL src, LDS linear.
__global__ void __launch_bounds__(256, 2) k_gemm(const char* __restrict__ L0,
                                                 const char* __restrict__ L1,
                                                 const char* __restrict__ L2,
                                                 const char* __restrict__ BT,
                                                 float* __restrict__ C) {
  __shared__ char A0[2][128 * 64];
  __shared__ char A1[2][128 * 64];
  __shared__ char A2[2][128 * 64];
  __shared__ char Bq[2][128 * 64];
  int tid = threadIdx.x;
  // XCD-chunked swizzle: each XCD owns one gy (A-panel stays in its L2)
  int id = (blockIdx.x & 7) * 64 + (blockIdx.x >> 3);
  int gy = id >> 6, gx = id & 63;
  int wave = tid >> 6, lane = tid & 63;
  int wr = wave >> 1, wc = wave & 1;
  int lr = lane & 15, lg = lane >> 4;

  i32x4 accA[4][4], acc2[4][4];
#pragma unroll
  for (int m = 0; m < 4; ++m)
#pragma unroll
    for (int nn = 0; nn < 4; ++nn) { accA[m][nn] = (i32x4)0; acc2[m][nn] = (i32x4)0; }

  // staging: round j covers rows j*64..j*64+63; granule p=j*256+tid
  size_t ga[2], gb[2];
  unsigned ldsd[2];
#pragma unroll
  for (int j = 0; j < 2; ++j) {
    int row = j * 64 + (tid >> 2);
    int src = (tid & 3) ^ ((row ^ (row >> 2)) & 3);
    ga[j] = (size_t)(gy * 128 + row) * KP + src * 16;
    gb[j] = (size_t)(gx * 128 + row) * KP + src * 16;
    ldsd[j] = (unsigned)(j * 4096 + tid * 16);
  }

  // fragment byte offsets
  int offA[4], offB[4];
#pragma unroll
  for (int m = 0; m < 4; ++m) {
    int ra = wr * 64 + m * 16 + lr;
    offA[m] = ra * 64 + ((lg ^ ((ra ^ (ra >> 2)) & 3)) * 16);
  }
#pragma unroll
  for (int nn = 0; nn < 4; ++nn) {
    int rb = wc * 64 + nn * 16 + lr;
    offB[nn] = rb * 64 + ((lg ^ ((rb ^ (rb >> 2)) & 3)) * 16);
  }

  // prologue: stage K-step 0 -> buf 0
#pragma unroll
  for (int j = 0; j < 2; ++j) {
    GLL16(L0 + ga[j], (char*)&A0[0][0] + ldsd[j]);
    GLL16(L1 + ga[j], (char*)&A1[0][0] + ldsd[j]);
    GLL16(L2 + ga[j], (char*)&A2[0][0] + ldsd[j]);
    GLL16(BT + gb[j], (char*)&Bq[0][0] + ldsd[j]);
  }
  __syncthreads();

  for (int ks = 0; ks < NK; ++ks) {
    int cur = ks & 1;
    if (ks + 1 < NK) {
      size_t ko = (size_t)(ks + 1) * 64;
      int nxt = cur ^ 1;
#pragma unroll
      for (int j = 0; j < 2; ++j) {
        GLL16(L0 + ga[j] + ko, (char*)&A0[nxt][0] + ldsd[j]);
        GLL16(L1 + ga[j] + ko, (char*)&A1[nxt][0] + ldsd[j]);
        GLL16(L2 + ga[j] + ko, (char*)&A2[nxt][0] + ldsd[j]);
        GLL16(BT + gb[j] + ko, (char*)&Bq[nxt][0] + ldsd[j]);
      }
    }
    i32x4 a0[4], a1[4], a2v[4], bv[4], b6[4];
#pragma unroll
    for (int m = 0; m < 4; ++m) {
      a0[m]  = *(const i32x4*)(&A0[cur][0] + offA[m]);
      a1[m]  = *(const i32x4*)(&A1[cur][0] + offA[m]);
      a2v[m] = *(const i32x4*)(&A2[cur][0] + offA[m]);
    }
#pragma unroll
    for (int nn = 0; nn < 4; ++nn) {
      bv[nn] = *(const i32x4*)(&Bq[cur][0] + offB[nn]);
      b6[nn] = bv[nn] << 6;          // bytes are 0/1 -> 0/64, no carries
    }
    __builtin_amdgcn_s_setprio(1);
#pragma unroll
    for (int m = 0; m < 4; ++m)
#pragma unroll
      for (int nn = 0; nn < 4; ++nn) {
        accA[m][nn] = __builtin_amdgcn_mfma_i32_16x16x64_i8(a0[m], bv[nn], accA[m][nn], 0, 0, 0);
        accA[m][nn] = __builtin_amdgcn_mfma_i32_16x16x64_i8(a1[m], b6[nn], accA[m][nn], 0, 0, 0);
        acc2[m][nn] = __builtin_amdgcn_mfma_i32_16x16x64_i8(a2v[m], bv[nn], acc2[m][nn], 0, 0, 0);
      }
    __builtin_amdgcn_s_setprio(0);
    __syncthreads();
  }

#pragma unroll
  for (int m = 0; m < 4; ++m)
#pragma unroll
    for (int nn = 0; nn < 4; ++nn) {
      int o = gy * 128 + wr * 64 + m * 16 + lg * 4;
      int c = gx * 128 + wc * 64 + nn * 16 + lr;
#pragma unroll
      for (int reg = 0; reg < 4; ++reg) {
        float u = fmaf(4096.0f, (float)acc2[m][nn][reg], (float)accA[m][nn][reg])
                  * (1.0f / 131072.0f);
        C[(size_t)(o + reg) * NC + c] = u;
      }
    }
}

// ---------------- K3: psp+spike + fused partial Wv2 dot -> a2part -----------
// block (og, n): 64 channels; spikes kept in LDS, partial sums written per og.
__global__ void __launch_bounds__(256) k_spk1(const float* __restrict__ C,
                                              const float* __restrict__ Wv2,
                                              float* __restrict__ a2part) {
  __shared__ float tile[128 * 65];   // [t_local][ch] 33.3 KB
  __shared__ char  spkb[128 * 68];   // [t_local][ch]  8.7 KB
  __shared__ float w2s[O2][64];      // 2.5 KB
  int og = blockIdx.x, n = blockIdx.y;
  int tid = threadIdx.x;
  for (int i = tid; i < O2 * 64; i += 256)
    w2s[i >> 6][i & 63] = Wv2[(i >> 6) * O1 + og * 64 + (i & 63)];
  float p = 0.f, r = 0.f;
  for (int tc = 0; tc < 4; ++tc) {
    // coop load 64 ch x 128 t (f32x4), scatter col-major
#pragma unroll
    for (int i = 0; i < 8; ++i) {
      int idx = i * 256 + tid;
      int row = idx >> 5, c4 = idx & 31;
      f32x4 v = *(const f32x4*)(C + (size_t)(og * 64 + row) * NC + n * TP + tc * 128 + c4 * 4);
#pragma unroll
      for (int j = 0; j < 4; ++j) tile[(c4 * 4 + j) * 65 + row] = v[j];
    }
    __syncthreads();
    if (tid < 64) {
      float pp = p, rr = r;
      for (int i = 0; i < 128; i += 8) {
        float u[8];
#pragma unroll
        for (int j = 0; j < 8; ++j) u[j] = tile[(i + j) * 65 + tid];
#pragma unroll
        for (int j = 0; j < 8; ++j) {
          pp = DSR * pp + u[j];
          float v = pp + rr;
          bool s = (v >= THETA);
          rr = DREF * (rr - (s ? REFAMP : 0.f));
          spkb[(i + j) * 68 + tid] = s ? (char)1 : (char)0;
        }
      }
      p = pp; r = rr;
    }
    __syncthreads();
    // partial dot: thread t (0..127) over 64 rows, 10 outputs
    if (tid < 128) {
      float acc[O2];
#pragma unroll
      for (int o = 0; o < O2; ++o) acc[o] = 0.f;
      for (int row = 0; row < 64; ++row) {
        float s = (spkb[tid * 68 + row] != 0) ? 1.f : 0.f;
#pragma unroll
        for (int o = 0; o < O2; ++o) acc[o] = fmaf(w2s[o][row], s, acc[o]);
      }
      int tglob = tc * 128 + tid;
#pragma unroll
      for (int o = 0; o < O2; ++o)
        a2part[(((size_t)og * NB + n) * O2 + o) * TP + tglob] = acc[o];
    }
    __syncthreads();
  }
}

// ---------------- K5: reduce a2part -> psp+spike -> Wf -> psp+spike ---------
__global__ void __launch_bounds__(512) k_finish(const float* __restrict__ a2part,
                                                const float* __restrict__ s_tact,
                                                const float* __restrict__ Wf,
                                                float* __restrict__ out) {
  __shared__ float u2[TP * 12];   // [t][o] 24.6 KB
  __shared__ float af[TP * 21];   // [t][o] 43 KB
  int n = blockIdx.x, t = threadIdx.x;
  // phase A: reduce partials (coalesced along t)
#pragma unroll
  for (int o = 0; o < O2; ++o) {
    float s = 0.f;
#pragma unroll
    for (int og = 0; og < NB; ++og)
      s += a2part[(((size_t)og * NB + n) * O2 + o) * TP + t];
    u2[t * 12 + o] = s;
  }
  __syncthreads();
  // phase B: vis psp+spike (10 lanes, batched reads)
  if (t < O2) {
    float p = 0.f, r = 0.f;
    for (int i = 0; i < TT; i += 10) {
      float u[10];
#pragma unroll
      for (int j = 0; j < 10; ++j) u[j] = u2[(i + j) * 12 + t];
#pragma unroll
      for (int j = 0; j < 10; ++j) {
        p = DSR * p + u[j];
        float v = p + r;
        bool s = (v >= THETA);
        r = DREF * (r - (s ? REFAMP : 0.f));
        u2[(i + j) * 12 + t] = s ? 1.f : 0.f;
      }
    }
  }
  __syncthreads();
  // phase C: af = Wf @ [s_tact ; s_vis]
  if (t < TT) {
    float acc[OF];
#pragma unroll
    for (int o = 0; o < OF; ++o) acc[o] = 0.f;
    for (int f = 0; f < OT; ++f) {
      float s = s_tact[((size_t)n * OT + f) * TT + t];
#pragma unroll
      for (int o = 0; o < OF; ++o) acc[o] = fmaf(Wf[o * 60 + f], s, acc[o]);
    }
#pragma unroll
    for (int f = 0; f < O2; ++f) {
      float s = u2[t * 12 + f];
#pragma unroll
      for (int o = 0; o < OF; ++o) acc[o] = fmaf(Wf[o * 60 + OT + f], s, acc[o]);
    }
#pragma unroll
    for (int o = 0; o < OF; ++o) af[t * 21 + o] = acc[o];
  }
  __syncthreads();
  // phase D: final psp+spike -> out (20 lanes, batched reads)
  if (t < OF) {
    float p = 0.f, r = 0.f;
    float* op = out + ((size_t)n * OF + t) * TT;
    for (int i = 0; i < TT; i += 10) {
      float u[10];
#pragma unroll
      for (int j = 0; j < 10; ++j) u[j] = af[(i + j) * 21 + t];
#pragma unroll
      for (int j = 0; j < 10; ++j) {
        p = DSR * p + u[j];
        float v = p + r;
        bool s = (v >= THETA);
        r = DREF * (r - (s ? REFAMP : 0.f));
        op[i + j] = s ? 1.f : 0.f;
      }
    }
  }
}

extern "C" void kernel_launch(void* const* d_in, const int* in_sizes, int n_in,
                              void* d_out, int out_size, void* d_ws, size_t ws_size,
                              hipStream_t stream) {
  (void)in_sizes; (void)n_in; (void)out_size; (void)ws_size;
  const float* xt  = (const float*)d_in[0];
  const float* xv  = (const float*)d_in[1];
  const float* Wt  = (const float*)d_in[2];
  const float* Wv1 = (const float*)d_in[3];
  const float* Wv2 = (const float*)d_in[4];
  const float* Wf  = (const float*)d_in[5];
  float* out = (float*)d_out;

  char* ws = (char*)d_ws;
  size_t off = 0;
  auto carve = [&](size_t bytes) {
    char* p = ws + off;
    off += (bytes + 255) & ~(size_t)255;
    return p;
  };
  char*  L0    = carve((size_t)O1 * KP);
  char*  L1    = carve((size_t)O1 * KP);
  char*  L2    = carve((size_t)O1 * KP);
  char*  xbT   = carve((size_t)NB * TP * KP);
  float* a1    = (float*)carve((size_t)O1 * NC * 4);
  float* stact = (float*)carve((size_t)NB * OT * TT * 4);
  float* a2p   = (float*)carve((size_t)NB * NB * O2 * TP * 4);

  k_split3<<<dim3((O1 * KP + 255) / 256), dim3(256), 0, stream>>>(Wv1, L0, L1, L2);
  k_xpose<<<dim3(KP / 64, TP / 64, NB), dim3(256), 0, stream>>>(xv, xbT);
  k_tact<<<dim3(NB * 2), dim3(512), 0, stream>>>(xt, Wt, stact);
  k_gemm<<<dim3(512), dim3(256), 0, stream>>>(L0, L1, L2, xbT, a1);
  k_spk1<<<dim3(16, NB), dim3(256), 0, stream>>>(a1, Wv2, a2p);
  k_finish<<<dim3(NB), dim3(512), 0, stream>>>(a2p, stact, Wf, out);
}

// Round 6
// 382.443 us; speedup vs baseline: 2.3201x; 1.1157x over previous
//
#include <hip/hip_runtime.h>
#include <stdint.h>

#define DSR   0.90483741803595952f   // exp(-1/10)
#define DREF  0.36787944117144233f   // exp(-1)
#define THETA 10.0f
#define REFAMP 20.0f                 // SCALE_REF * THETA

#define NB 16
#define TT 500
#define TP 512
#define F1 6300
#define KP 6400      // K padded (multiple of 128)
#define NKS 50       // KP/128
#define BROW 800     // bitmap bytes per row (KP/8)
#define O1 1024
#define NC 8192      // NB * TP columns
#define FT 156
#define OT 50
#define O2 10
#define OF 20

typedef __attribute__((ext_vector_type(4))) float f32x4;
typedef __attribute__((ext_vector_type(4))) int   i32x4;

#define GLL16(g, l) __builtin_amdgcn_global_load_lds( \
    (const __attribute__((address_space(1))) void*)(g), \
    (__attribute__((address_space(3))) void*)(l), 16, 0, 0)

// ---------------- K0a: Wv1 -> 3 signed base-64 int8 digit planes ------------
// w ~= (l0 + 64*l1 + 4096*l2) * 2^-17, digits in [-32,31]
__global__ void k_split3(const float* __restrict__ W, char* __restrict__ L0,
                         char* __restrict__ L1, char* __restrict__ L2) {
  int idx = blockIdx.x * 256 + threadIdx.x;
  if (idx >= O1 * KP) return;
  int o = idx / KP, f = idx - o * KP;
  float w = (f < F1) ? W[o * F1 + f] : 0.0f;
  int Wq = (int)lrintf(w * 131072.0f);       // 2^17
  int l0 = ((Wq + 32) & 63) - 32;  int W1 = (Wq - l0) >> 6;
  int l1 = ((W1 + 32) & 63) - 32;  int l2 = (W1 - l1) >> 6;
  L0[idx] = (char)l0;
  L1[idx] = (char)l1;
  L2[idx] = (char)l2;
}

// ---------------- K0b: xv (n,f,t) -> bitmap BB[(n*512+t)*800 + f/8] ---------
__global__ void k_xposeB(const float* __restrict__ xv, unsigned char* __restrict__ BB) {
  __shared__ float tile[64][65];
  int ft = blockIdx.x;   // 0..99 (f-group of 64)
  int tt = blockIdx.y;   // 0..7  (t-group of 64)
  int n  = blockIdx.z;
  int lane = threadIdx.x & 63, w = threadIdx.x >> 6;
  int f0 = ft * 64, t0 = tt * 64;
#pragma unroll
  for (int i = 0; i < 16; ++i) {
    int fl = w * 16 + i;
    int f = f0 + fl, t = t0 + lane;
    float v = (f < F1 && t < TT) ? xv[((size_t)n * F1 + f) * TT + t] : 0.0f;
    tile[fl][lane] = v;
  }
  __syncthreads();
#pragma unroll
  for (int i = 0; i < 16; ++i) {
    int tl = w * 16 + i;
    unsigned long long mask = __ballot(tile[lane][tl] != 0.0f);
    if (lane == 0)
      *(unsigned long long*)(BB + ((size_t)n * TP + t0 + tl) * BROW + ft * 8) = mask;
  }
}

// ---------------- K1: tactile: dense(Wt,xt) -> psp -> spike -> s_tact -------
__global__ void __launch_bounds__(512) k_tact(const float* __restrict__ xt,
                                              const float* __restrict__ Wt,
                                              float* __restrict__ s_tact) {
  __shared__ float atv[TP * 26];   // [t][o]
  int n = blockIdx.x >> 1, half = blockIdx.x & 1;
  int t = threadIdx.x;
  if (t < TT) {
    float acc[25];
#pragma unroll
    for (int o = 0; o < 25; ++o) acc[o] = 0.f;
    for (int f = 0; f < FT; ++f) {
      float x = xt[((size_t)n * FT + f) * TT + t];
#pragma unroll
      for (int o = 0; o < 25; ++o)
        acc[o] = fmaf(Wt[(half * 25 + o) * FT + f], x, acc[o]);
    }
#pragma unroll
    for (int o = 0; o < 25; ++o) atv[t * 26 + o] = acc[o];
  }
  __syncthreads();
  if (t < 25) {
    float p = 0.f, r = 0.f;
    float* op = s_tact + ((size_t)n * OT + half * 25 + t) * TT;
    for (int i = 0; i < TT; i += 10) {
      float u[10];
#pragma unroll
      for (int j = 0; j < 10; ++j) u[j] = atv[(i + j) * 26 + t];
#pragma unroll
      for (int j = 0; j < 10; ++j) {
        p = DSR * p + u[j];
        float v = p + r;
        bool s = (v >= THETA);
        r = DREF * (r - (s ? REFAMP : 0.f));
        op[i + j] = s ? 1.f : 0.f;
      }
    }
  }
}

// ---------------- K2: GEMM  C = W * B^T, i8 MFMA, bitmap B ------------------
// BM=128, BN=256, BK=128, 512 thr (8 waves 2x4), dbuf LDS 104KB.
// A rows 128B (R4-proven conflict-free geometry), granule-XOR on GLOBAL src.
// B expanded from bits in registers: ((x>>4w)&0xF)*0x00204081 & 0x01010101.
__global__ void __launch_bounds__(512) k_gemm(const char* __restrict__ L0,
                                              const char* __restrict__ L1,
                                              const char* __restrict__ L2,
                                              const unsigned char* __restrict__ BB,
                                              float* __restrict__ C) {
  __shared__ char A0[2][128 * 128];          // 16 KB x2
  __shared__ char A1[2][128 * 128];
  __shared__ char A2[2][128 * 128];
  __shared__ unsigned char Bb[2][256 * 16];  // 4 KB x2
  int tid = threadIdx.x;
  int bid = blockIdx.x;
  int gy = bid & 7, gx = bid >> 3;           // XCD owns one gy: A panel L2-resident
  int wave = tid >> 6, lane = tid & 63;
  int wr = wave >> 2, wc = wave & 3;         // 2 x 4 wave grid, wave tile 64x64
  int lr = lane & 15, lg = lane >> 4;

  i32x4 accA[4][4], acc2[4][4];
#pragma unroll
  for (int m = 0; m < 4; ++m)
#pragma unroll
    for (int nn = 0; nn < 4; ++nn) { accA[m][nn] = (i32x4)0; acc2[m][nn] = (i32x4)0; }

  // A staging: round j: granule p = j*512+tid; row = p>>3; phys m = tid&7
  size_t ga[2];
  unsigned ldsa[2];
#pragma unroll
  for (int j = 0; j < 2; ++j) {
    int p = j * 512 + tid;
    int row = p >> 3;
    int src = (tid & 7) ^ (row & 7);
    ga[j] = (size_t)(gy * 128 + row) * KP + src * 16;
    ldsa[j] = (unsigned)p * 16u;
  }
  // B staging: tid<256: row=tid, 16B per row per K-step
  size_t gb = (size_t)(gx * 256 + (tid & 255)) * BROW;
  unsigned ldsb = (unsigned)(tid & 255) * 16u;

  // A fragment byte offsets: row ra, k-sub kk, logical granule (kk*4+lg)
  int offA[4][2];
#pragma unroll
  for (int m = 0; m < 4; ++m) {
    int ra = wr * 64 + m * 16 + lr;
#pragma unroll
    for (int kk = 0; kk < 2; ++kk)
      offA[m][kk] = ra * 128 + (((kk * 4 + lg) ^ (ra & 7)) * 16);
  }
  int browf[4];   // B bitmap row per nn
#pragma unroll
  for (int nn = 0; nn < 4; ++nn) browf[nn] = (wc * 64 + nn * 16 + lr) * 16;

  // prologue: stage ks=0 -> buf 0
#pragma unroll
  for (int j = 0; j < 2; ++j) {
    GLL16(L0 + ga[j], (char*)&A0[0][0] + ldsa[j]);
    GLL16(L1 + ga[j], (char*)&A1[0][0] + ldsa[j]);
    GLL16(L2 + ga[j], (char*)&A2[0][0] + ldsa[j]);
  }
  if (tid < 256) GLL16(BB + gb, (char*)&Bb[0][0] + ldsb);
  __syncthreads();

  for (int ks = 0; ks < NKS; ++ks) {
    int cur = ks & 1;
    if (ks + 1 < NKS) {
      int nxt = cur ^ 1;
      size_t ko = (size_t)(ks + 1) * 128;
#pragma unroll
      for (int j = 0; j < 2; ++j) {
        GLL16(L0 + ga[j] + ko, (char*)&A0[nxt][0] + ldsa[j]);
        GLL16(L1 + ga[j] + ko, (char*)&A1[nxt][0] + ldsa[j]);
        GLL16(L2 + ga[j] + ko, (char*)&A2[nxt][0] + ldsa[j]);
      }
      if (tid < 256) GLL16(BB + gb + (size_t)(ks + 1) * 16, (char*)&Bb[nxt][0] + ldsb);
    }
#pragma unroll
    for (int kk = 0; kk < 2; ++kk) {
      // expand B fragments from bits
      i32x4 bv[4], b6[4];
#pragma unroll
      for (int nn = 0; nn < 4; ++nn) {
        unsigned x = *(const unsigned short*)(&Bb[cur][browf[nn] + kk * 8 + lg * 2]);
#pragma unroll
        for (int w = 0; w < 4; ++w) {
          unsigned nib = (x >> (4 * w)) & 0xFu;
          bv[nn][w] = (int)((nib * 0x00204081u) & 0x01010101u);
        }
        b6[nn] = bv[nn] << 6;
      }
      i32x4 a0[4], a1[4], a2v[4];
#pragma unroll
      for (int m = 0; m < 4; ++m) {
        a0[m]  = *(const i32x4*)(&A0[cur][0] + offA[m][kk]);
        a1[m]  = *(const i32x4*)(&A1[cur][0] + offA[m][kk]);
        a2v[m] = *(const i32x4*)(&A2[cur][0] + offA[m][kk]);
      }
      __builtin_amdgcn_s_setprio(1);
#pragma unroll
      for (int m = 0; m < 4; ++m)
#pragma unroll
        for (int nn = 0; nn < 4; ++nn) {
          accA[m][nn] = __builtin_amdgcn_mfma_i32_16x16x64_i8(a0[m], bv[nn], accA[m][nn], 0, 0, 0);
          accA[m][nn] = __builtin_amdgcn_mfma_i32_16x16x64_i8(a1[m], b6[nn], accA[m][nn], 0, 0, 0);
          acc2[m][nn] = __builtin_amdgcn_mfma_i32_16x16x64_i8(a2v[m], bv[nn], acc2[m][nn], 0, 0, 0);
        }
      __builtin_amdgcn_s_setprio(0);
    }
    __syncthreads();
  }

#pragma unroll
  for (int m = 0; m < 4; ++m)
#pragma unroll
    for (int nn = 0; nn < 4; ++nn) {
      int o = gy * 128 + wr * 64 + m * 16 + lg * 4;
      int c = gx * 256 + wc * 64 + nn * 16 + lr;
#pragma unroll
      for (int reg = 0; reg < 4; ++reg) {
        float u = fmaf(4096.0f, (float)acc2[m][nn][reg], (float)accA[m][nn][reg])
                  * (1.0f / 131072.0f);
        C[(size_t)(o + reg) * NC + c] = u;
      }
    }
}

// ---------------- K3: psp+spike + fused partial Wv2 dot -> a2part -----------
__global__ void __launch_bounds__(256) k_spk1(const float* __restrict__ C,
                                              const float* __restrict__ Wv2,
                                              float* __restrict__ a2part) {
  __shared__ float tile[128 * 65];   // [t_local][ch] 33.3 KB
  __shared__ char  spkb[128 * 68];   // [t_local][ch]  8.7 KB
  __shared__ float w2s[O2][64];      // 2.5 KB
  int og = blockIdx.x, n = blockIdx.y;
  int tid = threadIdx.x;
  for (int i = tid; i < O2 * 64; i += 256)
    w2s[i >> 6][i & 63] = Wv2[(i >> 6) * O1 + og * 64 + (i & 63)];
  float p = 0.f, r = 0.f;
  for (int tc = 0; tc < 4; ++tc) {
#pragma unroll
    for (int i = 0; i < 8; ++i) {
      int idx = i * 256 + tid;
      int row = idx >> 5, c4 = idx & 31;
      f32x4 v = *(const f32x4*)(C + (size_t)(og * 64 + row) * NC + n * TP + tc * 128 + c4 * 4);
#pragma unroll
      for (int j = 0; j < 4; ++j) tile[(c4 * 4 + j) * 65 + row] = v[j];
    }
    __syncthreads();
    if (tid < 64) {
      float pp = p, rr = r;
      for (int i = 0; i < 128; i += 8) {
        float u[8];
#pragma unroll
        for (int j = 0; j < 8; ++j) u[j] = tile[(i + j) * 65 + tid];
#pragma unroll
        for (int j = 0; j < 8; ++j) {
          pp = DSR * pp + u[j];
          float v = pp + rr;
          bool s = (v >= THETA);
          rr = DREF * (rr - (s ? REFAMP : 0.f));
          spkb[(i + j) * 68 + tid] = s ? (char)1 : (char)0;
        }
      }
      p = pp; r = rr;
    }
    __syncthreads();
    if (tid < 128) {
      float acc[O2];
#pragma unroll
      for (int o = 0; o < O2; ++o) acc[o] = 0.f;
      for (int row = 0; row < 64; ++row) {
        float s = (spkb[tid * 68 + row] != 0) ? 1.f : 0.f;
#pragma unroll
        for (int o = 0; o < O2; ++o) acc[o] = fmaf(w2s[o][row], s, acc[o]);
      }
      int tglob = tc * 128 + tid;
#pragma unroll
      for (int o = 0; o < O2; ++o)
        a2part[(((size_t)og * NB + n) * O2 + o) * TP + tglob] = acc[o];
    }
    __syncthreads();
  }
}

// ---------------- K5: reduce a2part -> psp+spike -> Wf -> psp+spike ---------
__global__ void __launch_bounds__(512) k_finish(const float* __restrict__ a2part,
                                                const float* __restrict__ s_tact,
                                                const float* __restrict__ Wf,
                                                float* __restrict__ out) {
  __shared__ float u2[TP * 12];   // [t][o]
  __shared__ float af[TP * 21];   // [t][o]
  int n = blockIdx.x, t = threadIdx.x;
#pragma unroll
  for (int o = 0; o < O2; ++o) {
    float s = 0.f;
#pragma unroll
    for (int og = 0; og < NB; ++og)
      s += a2part[(((size_t)og * NB + n) * O2 + o) * TP + t];
    u2[t * 12 + o] = s;
  }
  __syncthreads();
  if (t < O2) {
    float p = 0.f, r = 0.f;
    for (int i = 0; i < TT; i += 10) {
      float u[10];
#pragma unroll
      for (int j = 0; j < 10; ++j) u[j] = u2[(i + j) * 12 + t];
#pragma unroll
      for (int j = 0; j < 10; ++j) {
        p = DSR * p + u[j];
        float v = p + r;
        bool s = (v >= THETA);
        r = DREF * (r - (s ? REFAMP : 0.f));
        u2[(i + j) * 12 + t] = s ? 1.f : 0.f;
      }
    }
  }
  __syncthreads();
  if (t < TT) {
    float acc[OF];
#pragma unroll
    for (int o = 0; o < OF; ++o) acc[o] = 0.f;
    for (int f = 0; f < OT; ++f) {
      float s = s_tact[((size_t)n * OT + f) * TT + t];
#pragma unroll
      for (int o = 0; o < OF; ++o) acc[o] = fmaf(Wf[o * 60 + f], s, acc[o]);
    }
#pragma unroll
    for (int f = 0; f < O2; ++f) {
      float s = u2[t * 12 + f];
#pragma unroll
      for (int o = 0; o < OF; ++o) acc[o] = fmaf(Wf[o * 60 + OT + f], s, acc[o]);
    }
#pragma unroll
    for (int o = 0; o < OF; ++o) af[t * 21 + o] = acc[o];
  }
  __syncthreads();
  if (t < OF) {
    float p = 0.f, r = 0.f;
    float* op = out + ((size_t)n * OF + t) * TT;
    for (int i = 0; i < TT; i += 10) {
      float u[10];
#pragma unroll
      for (int j = 0; j < 10; ++j) u[j] = af[(i + j) * 21 + t];
#pragma unroll
      for (int j = 0; j < 10; ++j) {
        p = DSR * p + u[j];
        float v = p + r;
        bool s = (v >= THETA);
        r = DREF * (r - (s ? REFAMP : 0.f));
        op[i + j] = s ? 1.f : 0.f;
      }
    }
  }
}

extern "C" void kernel_launch(void* const* d_in, const int* in_sizes, int n_in,
                              void* d_out, int out_size, void* d_ws, size_t ws_size,
                              hipStream_t stream) {
  (void)in_sizes; (void)n_in; (void)out_size; (void)ws_size;
  const float* xt  = (const float*)d_in[0];
  const float* xv  = (const float*)d_in[1];
  const float* Wt  = (const float*)d_in[2];
  const float* Wv1 = (const float*)d_in[3];
  const float* Wv2 = (const float*)d_in[4];
  const float* Wf  = (const float*)d_in[5];
  float* out = (float*)d_out;

  char* ws = (char*)d_ws;
  size_t off = 0;
  auto carve = [&](size_t bytes) {
    char* p = ws + off;
    off += (bytes + 255) & ~(size_t)255;
    return p;
  };
  char*          L0    = carve((size_t)O1 * KP);
  char*          L1    = carve((size_t)O1 * KP);
  char*          L2    = carve((size_t)O1 * KP);
  unsigned char* BBm   = (unsigned char*)carve((size_t)NB * TP * BROW);
  float*         a1    = (float*)carve((size_t)O1 * NC * 4);
  float*         stact = (float*)carve((size_t)NB * OT * TT * 4);
  float*         a2p   = (float*)carve((size_t)NB * NB * O2 * TP * 4);

  k_split3<<<dim3((O1 * KP) / 256), dim3(256), 0, stream>>>(Wv1, L0, L1, L2);
  k_xposeB<<<dim3(100, 8, NB), dim3(256), 0, stream>>>(xv, BBm);
  k_tact<<<dim3(NB * 2), dim3(512), 0, stream>>>(xt, Wt, stact);
  k_gemm<<<dim3(256), dim3(512), 0, stream>>>(L0, L1, L2, BBm, a1);
  k_spk1<<<dim3(16, NB), dim3(256), 0, stream>>>(a1, Wv2, a2p);
  k_finish<<<dim3(NB), dim3(512), 0, stream>>>(a2p, stact, Wf, out);
}

// Round 7
// 376.294 us; speedup vs baseline: 2.3580x; 1.0163x over previous
//
#include <hip/hip_runtime.h>
#include <stdint.h>

#define DSR   0.90483741803595952f   // exp(-1/10)
#define DREF  0.36787944117144233f   // exp(-1)
#define THETA 10.0f
#define REFAMP 20.0f                 // SCALE_REF * THETA

#define NB 16
#define TT 500
#define TP 512
#define F1 6300
#define KP 6400      // K padded (multiple of 128)
#define NKS 50       // KP/128
#define BROW 800     // bitmap bytes per row (KP/8)
#define O1 1024
#define NC 8192      // NB * TP columns
#define FT 156
#define OT 50
#define O2 10
#define OF 20

typedef __attribute__((ext_vector_type(4)))  float f32x4;
typedef __attribute__((ext_vector_type(4)))  int   i32x4;
typedef __attribute__((ext_vector_type(16))) int   i32x16;

#define GLL16(g, l) __builtin_amdgcn_global_load_lds( \
    (const __attribute__((address_space(1))) void*)(g), \
    (__attribute__((address_space(3))) void*)(l), 16, 0, 0)

// ---------------- K0a: Wv1 -> 3 signed base-64 int8 digit planes ------------
// w ~= (l0 + 64*l1 + 4096*l2) * 2^-17, digits in [-32,31]
__global__ void k_split3(const float* __restrict__ W, char* __restrict__ L0,
                         char* __restrict__ L1, char* __restrict__ L2) {
  int idx = blockIdx.x * 256 + threadIdx.x;
  if (idx >= O1 * KP) return;
  int o = idx / KP, f = idx - o * KP;
  float w = (f < F1) ? W[o * F1 + f] : 0.0f;
  int Wq = (int)lrintf(w * 131072.0f);       // 2^17
  int l0 = ((Wq + 32) & 63) - 32;  int W1 = (Wq - l0) >> 6;
  int l1 = ((W1 + 32) & 63) - 32;  int l2 = (W1 - l1) >> 6;
  L0[idx] = (char)l0;
  L1[idx] = (char)l1;
  L2[idx] = (char)l2;
}

// ---------------- K0b: xv (n,f,t) -> bitmap BB[(n*512+t)*800 + f/8] ---------
__global__ void k_xposeB(const float* __restrict__ xv, unsigned char* __restrict__ BB) {
  __shared__ float tile[64][65];
  int ft = blockIdx.x;   // 0..99 (f-group of 64)
  int tt = blockIdx.y;   // 0..7  (t-group of 64)
  int n  = blockIdx.z;
  int lane = threadIdx.x & 63, w = threadIdx.x >> 6;
  int f0 = ft * 64, t0 = tt * 64;
#pragma unroll
  for (int i = 0; i < 16; ++i) {
    int fl = w * 16 + i;
    int f = f0 + fl, t = t0 + lane;
    float v = (f < F1 && t < TT) ? xv[((size_t)n * F1 + f) * TT + t] : 0.0f;
    tile[fl][lane] = v;
  }
  __syncthreads();
#pragma unroll
  for (int i = 0; i < 16; ++i) {
    int tl = w * 16 + i;
    unsigned long long mask = __ballot(tile[lane][tl] != 0.0f);
    if (lane == 0)
      *(unsigned long long*)(BB + ((size_t)n * TP + t0 + tl) * BROW + ft * 8) = mask;
  }
}

// ---------------- K1: tactile: dense(Wt,xt) -> psp -> spike -> s_tact -------
__global__ void __launch_bounds__(512) k_tact(const float* __restrict__ xt,
                                              const float* __restrict__ Wt,
                                              float* __restrict__ s_tact) {
  __shared__ float atv[TP * 26];   // [t][o]
  int n = blockIdx.x >> 1, half = blockIdx.x & 1;
  int t = threadIdx.x;
  if (t < TT) {
    float acc[25];
#pragma unroll
    for (int o = 0; o < 25; ++o) acc[o] = 0.f;
    for (int f = 0; f < FT; ++f) {
      float x = xt[((size_t)n * FT + f) * TT + t];
#pragma unroll
      for (int o = 0; o < 25; ++o)
        acc[o] = fmaf(Wt[(half * 25 + o) * FT + f], x, acc[o]);
    }
#pragma unroll
    for (int o = 0; o < 25; ++o) atv[t * 26 + o] = acc[o];
  }
  __syncthreads();
  if (t < 25) {
    float p = 0.f, r = 0.f;
    float* op = s_tact + ((size_t)n * OT + half * 25 + t) * TT;
    for (int i = 0; i < TT; i += 10) {
      float u[10];
#pragma unroll
      for (int j = 0; j < 10; ++j) u[j] = atv[(i + j) * 26 + t];
#pragma unroll
      for (int j = 0; j < 10; ++j) {
        p = DSR * p + u[j];
        float v = p + r;
        bool s = (v >= THETA);
        r = DREF * (r - (s ? REFAMP : 0.f));
        op[i + j] = s ? 1.f : 0.f;
      }
    }
  }
}

// ---------------- K2: GEMM  C = W * B^T, 32x32x32 i8 MFMA, bitmap B ---------
// BM=128, BN=256, BK=128, 512 thr (8 waves 2x4, wave tile 64x64), dbuf LDS
// 104KB (1 blk/CU), counted-vmcnt 2-deep pipeline (loads fly across barriers).
// 7 gload_lds per wave per K-step uniformly (B staged by even lanes everywhere).
__global__ void __launch_bounds__(512, 2) k_gemm(const char* __restrict__ L0,
                                                 const char* __restrict__ L1,
                                                 const char* __restrict__ L2,
                                                 const unsigned char* __restrict__ BB,
                                                 float* __restrict__ C) {
  __shared__ char A0[2][128 * 128];          // 16 KB x2
  __shared__ char A1[2][128 * 128];
  __shared__ char A2[2][128 * 128];
  __shared__ unsigned char Bb[2][256 * 16];  // 4 KB x2
  int tid = threadIdx.x;
  int bid = blockIdx.x;
  int gy = bid & 7, gx = bid >> 3;           // XCD owns one gy: A panel L2-resident
  int wave = tid >> 6, lane = tid & 63;
  int wr = wave >> 2, wc = wave & 3;         // 2 x 4 wave grid, wave tile 64x64
  int l31 = lane & 31, h = lane >> 5;

  i32x16 accA[2][2], acc2[2][2];
#pragma unroll
  for (int m = 0; m < 2; ++m)
#pragma unroll
    for (int nn = 0; nn < 2; ++nn) { accA[m][nn] = (i32x16)0; acc2[m][nn] = (i32x16)0; }

  // A staging: granule p = j*512 + tid; row = p>>3; phys slot = p&7;
  // source slot = phys ^ (row&7) (XOR involution on GLOBAL src, LDS linear)
  size_t ga[2];
  unsigned ldsa[2];
#pragma unroll
  for (int j = 0; j < 2; ++j) {
    int p = j * 512 + tid;
    int row = p >> 3;
    int src = (p & 7) ^ (row & 7);
    ga[j] = (size_t)(gy * 128 + row) * KP + src * 16;
    ldsa[j] = (unsigned)p * 16u;
  }
  // B staging: even lanes of EVERY wave (uniform 1 inst/wave): row = tid>>1
  int brow = tid >> 1;
  bool bstage = (tid & 1) == 0;
  size_t gb = (size_t)(gx * 256 + brow) * BROW;
  unsigned ldsb = (unsigned)brow * 16u;

  // A fragment byte offsets: row ra = wr*64+m*32+l31 (ra&7 == lane&7);
  // logical granule g = kk*2+h, phys = g ^ (ra&7)
  int offA[2][4];
#pragma unroll
  for (int m = 0; m < 2; ++m) {
    int ra = wr * 64 + m * 32 + l31;
#pragma unroll
    for (int kk = 0; kk < 4; ++kk)
      offA[m][kk] = ra * 128 + (((kk * 2 + h) ^ (ra & 7)) * 16);
  }
  // B bitmap fragment offsets: col row rb = wc*64+nn*32+l31, 2 bytes at h*2
  int offBb[2];
#pragma unroll
  for (int nn = 0; nn < 2; ++nn)
    offBb[nn] = (wc * 64 + nn * 32 + l31) * 16 + h * 2;

#define STAGE(ks, buf) do {                                              \
    size_t ko = (size_t)(ks) * 128;                                      \
    GLL16(L0 + ga[0] + ko, (char*)&A0[buf][0] + ldsa[0]);                \
    GLL16(L0 + ga[1] + ko, (char*)&A0[buf][0] + ldsa[1]);                \
    GLL16(L1 + ga[0] + ko, (char*)&A1[buf][0] + ldsa[0]);                \
    GLL16(L1 + ga[1] + ko, (char*)&A1[buf][0] + ldsa[1]);                \
    GLL16(L2 + ga[0] + ko, (char*)&A2[buf][0] + ldsa[0]);                \
    GLL16(L2 + ga[1] + ko, (char*)&A2[buf][0] + ldsa[1]);                \
    if (bstage) GLL16(BB + gb + (size_t)(ks) * 16, (char*)&Bb[buf][0] + ldsb); \
  } while (0)

  // prologue: 2-deep
  STAGE(0, 0);
  STAGE(1, 1);

  for (int ks = 0; ks < NKS; ++ks) {
    int cur = ks & 1;
    if (ks < NKS - 1) {
      asm volatile("s_waitcnt vmcnt(7)" ::: "memory");   // stage(ks) landed; stage(ks+1) in flight
    } else {
      asm volatile("s_waitcnt vmcnt(0)" ::: "memory");   // epilogue drain
    }
    __builtin_amdgcn_sched_barrier(0);
    __builtin_amdgcn_s_barrier();
    __builtin_amdgcn_sched_barrier(0);
#pragma unroll
    for (int kk = 0; kk < 4; ++kk) {
      // B expand from bits: 16 bits -> 16 i8 bytes
      i32x4 bv[2], b6[2];
#pragma unroll
      for (int nn = 0; nn < 2; ++nn) {
        unsigned x = *(const unsigned short*)(&Bb[cur][offBb[nn] + kk * 4]);
#pragma unroll
        for (int w = 0; w < 4; ++w) {
          unsigned nib = (x >> (4 * w)) & 0xFu;
          bv[nn][w] = (int)((nib * 0x00204081u) & 0x01010101u);
        }
        b6[nn] = bv[nn] << 6;    // bytes 0/1 -> 0/64
      }
      i32x4 a0[2], a1[2], a2v[2];
#pragma unroll
      for (int m = 0; m < 2; ++m) {
        a0[m]  = *(const i32x4*)(&A0[cur][0] + offA[m][kk]);
        a1[m]  = *(const i32x4*)(&A1[cur][0] + offA[m][kk]);
        a2v[m] = *(const i32x4*)(&A2[cur][0] + offA[m][kk]);
      }
      __builtin_amdgcn_s_setprio(1);
#pragma unroll
      for (int m = 0; m < 2; ++m)
#pragma unroll
        for (int nn = 0; nn < 2; ++nn) {
          accA[m][nn] = __builtin_amdgcn_mfma_i32_32x32x32_i8(a0[m], bv[nn], accA[m][nn], 0, 0, 0);
          accA[m][nn] = __builtin_amdgcn_mfma_i32_32x32x32_i8(a1[m], b6[nn], accA[m][nn], 0, 0, 0);
          acc2[m][nn] = __builtin_amdgcn_mfma_i32_32x32x32_i8(a2v[m], bv[nn], acc2[m][nn], 0, 0, 0);
        }
      __builtin_amdgcn_s_setprio(0);
    }
    __builtin_amdgcn_s_barrier();            // all reads of buf[cur] done
    __builtin_amdgcn_sched_barrier(0);
    if (ks + 2 < NKS) STAGE(ks + 2, cur);    // overwrite just-consumed buffer
  }
#undef STAGE

  // epilogue: C/D 32x32 layout: col = lane&31, row = (reg&3)+8*(reg>>2)+4*h
#pragma unroll
  for (int m = 0; m < 2; ++m)
#pragma unroll
    for (int nn = 0; nn < 2; ++nn) {
      int ob = gy * 128 + wr * 64 + m * 32;
      int cb = gx * 256 + wc * 64 + nn * 32 + l31;
#pragma unroll
      for (int reg = 0; reg < 16; ++reg) {
        int row = (reg & 3) + 8 * (reg >> 2) + 4 * h;
        float u = fmaf(4096.0f, (float)acc2[m][nn][reg], (float)accA[m][nn][reg])
                  * (1.0f / 131072.0f);
        C[(size_t)(ob + row) * NC + cb] = u;
      }
    }
}

// ---------------- K3: psp+spike + fused partial Wv2 dot -> a2part -----------
__global__ void __launch_bounds__(256) k_spk1(const float* __restrict__ C,
                                              const float* __restrict__ Wv2,
                                              float* __restrict__ a2part) {
  __shared__ float tile[128 * 65];   // [t_local][ch] 33.3 KB
  __shared__ char  spkb[128 * 68];   // [t_local][ch]  8.7 KB
  __shared__ float w2s[O2][64];      // 2.5 KB
  int og = blockIdx.x, n = blockIdx.y;
  int tid = threadIdx.x;
  for (int i = tid; i < O2 * 64; i += 256)
    w2s[i >> 6][i & 63] = Wv2[(i >> 6) * O1 + og * 64 + (i & 63)];
  float p = 0.f, r = 0.f;
  for (int tc = 0; tc < 4; ++tc) {
#pragma unroll
    for (int i = 0; i < 8; ++i) {
      int idx = i * 256 + tid;
      int row = idx >> 5, c4 = idx & 31;
      f32x4 v = *(const f32x4*)(C + (size_t)(og * 64 + row) * NC + n * TP + tc * 128 + c4 * 4);
#pragma unroll
      for (int j = 0; j < 4; ++j) tile[(c4 * 4 + j) * 65 + row] = v[j];
    }
    __syncthreads();
    if (tid < 64) {
      float pp = p, rr = r;
      for (int i = 0; i < 128; i += 8) {
        float u[8];
#pragma unroll
        for (int j = 0; j < 8; ++j) u[j] = tile[(i + j) * 65 + tid];
#pragma unroll
        for (int j = 0; j < 8; ++j) {
          pp = DSR * pp + u[j];
          float v = pp + rr;
          bool s = (v >= THETA);
          rr = DREF * (rr - (s ? REFAMP : 0.f));
          spkb[(i + j) * 68 + tid] = s ? (char)1 : (char)0;
        }
      }
      p = pp; r = rr;
    }
    __syncthreads();
    if (tid < 128) {
      float acc[O2];
#pragma unroll
      for (int o = 0; o < O2; ++o) acc[o] = 0.f;
      for (int row = 0; row < 64; ++row) {
        float s = (spkb[tid * 68 + row] != 0) ? 1.f : 0.f;
#pragma unroll
        for (int o = 0; o < O2; ++o) acc[o] = fmaf(w2s[o][row], s, acc[o]);
      }
      int tglob = tc * 128 + tid;
#pragma unroll
      for (int o = 0; o < O2; ++o)
        a2part[(((size_t)og * NB + n) * O2 + o) * TP + tglob] = acc[o];
    }
    __syncthreads();
  }
}

// ---------------- K5: reduce a2part -> psp+spike -> Wf -> psp+spike ---------
__global__ void __launch_bounds__(512) k_finish(const float* __restrict__ a2part,
                                                const float* __restrict__ s_tact,
                                                const float* __restrict__ Wf,
                                                float* __restrict__ out) {
  __shared__ float u2[TP * 12];   // [t][o]
  __shared__ float af[TP * 21];   // [t][o]
  int n = blockIdx.x, t = threadIdx.x;
#pragma unroll
  for (int o = 0; o < O2; ++o) {
    float s = 0.f;
#pragma unroll
    for (int og = 0; og < NB; ++og)
      s += a2part[(((size_t)og * NB + n) * O2 + o) * TP + t];
    u2[t * 12 + o] = s;
  }
  __syncthreads();
  if (t < O2) {
    float p = 0.f, r = 0.f;
    for (int i = 0; i < TT; i += 10) {
      float u[10];
#pragma unroll
      for (int j = 0; j < 10; ++j) u[j] = u2[(i + j) * 12 + t];
#pragma unroll
      for (int j = 0; j < 10; ++j) {
        p = DSR * p + u[j];
        float v = p + r;
        bool s = (v >= THETA);
        r = DREF * (r - (s ? REFAMP : 0.f));
        u2[(i + j) * 12 + t] = s ? 1.f : 0.f;
      }
    }
  }
  __syncthreads();
  if (t < TT) {
    float acc[OF];
#pragma unroll
    for (int o = 0; o < OF; ++o) acc[o] = 0.f;
    for (int f = 0; f < OT; ++f) {
      float s = s_tact[((size_t)n * OT + f) * TT + t];
#pragma unroll
      for (int o = 0; o < OF; ++o) acc[o] = fmaf(Wf[o * 60 + f], s, acc[o]);
    }
#pragma unroll
    for (int f = 0; f < O2; ++f) {
      float s = u2[t * 12 + f];
#pragma unroll
      for (int o = 0; o < OF; ++o) acc[o] = fmaf(Wf[o * 60 + OT + f], s, acc[o]);
    }
#pragma unroll
    for (int o = 0; o < OF; ++o) af[t * 21 + o] = acc[o];
  }
  __syncthreads();
  if (t < OF) {
    float p = 0.f, r = 0.f;
    float* op = out + ((size_t)n * OF + t) * TT;
    for (int i = 0; i < TT; i += 10) {
      float u[10];
#pragma unroll
      for (int j = 0; j < 10; ++j) u[j] = af[(i + j) * 21 + t];
#pragma unroll
      for (int j = 0; j < 10; ++j) {
        p = DSR * p + u[j];
        float v = p + r;
        bool s = (v >= THETA);
        r = DREF * (r - (s ? REFAMP : 0.f));
        op[i + j] = s ? 1.f : 0.f;
      }
    }
  }
}

extern "C" void kernel_launch(void* const* d_in, const int* in_sizes, int n_in,
                              void* d_out, int out_size, void* d_ws, size_t ws_size,
                              hipStream_t stream) {
  (void)in_sizes; (void)n_in; (void)out_size; (void)ws_size;
  const float* xt  = (const float*)d_in[0];
  const float* xv  = (const float*)d_in[1];
  const float* Wt  = (const float*)d_in[2];
  const float* Wv1 = (const float*)d_in[3];
  const float* Wv2 = (const float*)d_in[4];
  const float* Wf  = (const float*)d_in[5];
  float* out = (float*)d_out;

  char* ws = (char*)d_ws;
  size_t off = 0;
  auto carve = [&](size_t bytes) {
    char* p = ws + off;
    off += (bytes + 255) & ~(size_t)255;
    return p;
  };
  char*          L0    = carve((size_t)O1 * KP);
  char*          L1    = carve((size_t)O1 * KP);
  char*          L2    = carve((size_t)O1 * KP);
  unsigned char* BBm   = (unsigned char*)carve((size_t)NB * TP * BROW);
  float*         a1    = (float*)carve((size_t)O1 * NC * 4);
  float*         stact = (float*)carve((size_t)NB * OT * TT * 4);
  float*         a2p   = (float*)carve((size_t)NB * NB * O2 * TP * 4);

  k_split3<<<dim3((O1 * KP) / 256), dim3(256), 0, stream>>>(Wv1, L0, L1, L2);
  k_xposeB<<<dim3(100, 8, NB), dim3(256), 0, stream>>>(xv, BBm);
  k_tact<<<dim3(NB * 2), dim3(512), 0, stream>>>(xt, Wt, stact);
  k_gemm<<<dim3(256), dim3(512), 0, stream>>>(L0, L1, L2, BBm, a1);
  k_spk1<<<dim3(16, NB), dim3(256), 0, stream>>>(a1, Wv2, a2p);
  k_finish<<<dim3(NB), dim3(512), 0, stream>>>(a2p, stact, Wf, out);
}

// Round 8
// 329.361 us; speedup vs baseline: 2.6940x; 1.1425x over previous
//
#include <hip/hip_runtime.h>
#include <stdint.h>

#define DSR   0.90483741803595952f   // exp(-1/10)
#define DREF  0.36787944117144233f   // exp(-1)
#define THETA 10.0f
#define REFAMP 20.0f                 // SCALE_REF * THETA

#define NB 16
#define TT 500
#define TP 512
#define F1 6300
#define KP 6400      // K padded (multiple of 128)
#define NKS 50       // KP/128
#define O1 1024
#define NC 8192      // NB * TP columns
#define FT 156
#define OT 50
#define O2 10
#define OF 20

typedef __attribute__((ext_vector_type(4)))  float f32x4;
typedef __attribute__((ext_vector_type(4)))  int   i32x4;
typedef __attribute__((ext_vector_type(16))) int   i32x16;

#define GLL16(g, l) __builtin_amdgcn_global_load_lds( \
    (const __attribute__((address_space(1))) void*)(g), \
    (__attribute__((address_space(3))) void*)(l), 16, 0, 0)

// ============ K0: fused prep =================================================
// blocks [0,12800): xv -> bitmap Bg[ks(50)][col(8192)] 16B granules, bytes
//   permuted lane-h-major: byte d = h*8 + kk*2 + b holds k-bits kk*32+h*16+b*8.
// blocks [12800,13056): Wv1 -> 2 signed base-256 i8 planes, w*2^15 = h0+256*h1.
__global__ void __launch_bounds__(256) k_prep(const float* __restrict__ xv,
                                              const float* __restrict__ W,
                                              unsigned char* __restrict__ Bg,
                                              char* __restrict__ H0,
                                              char* __restrict__ H1) {
  __shared__ float tile[64][65];
  int bx = blockIdx.x, tid = threadIdx.x;
  if (bx < 12800) {
    int ft = bx % 100;
    int rem = bx / 100;
    int tt = rem & 7, n = rem >> 3;
    int lane = tid & 63, w = tid >> 6;
    int f0 = ft * 64, t0 = tt * 64;
#pragma unroll
    for (int i = 0; i < 16; ++i) {
      int fl = w * 16 + i;
      int f = f0 + fl, t = t0 + lane;
      float v = (f < F1 && t < TT) ? xv[((size_t)n * F1 + f) * TT + t] : 0.0f;
      tile[fl][lane] = v;
    }
    __syncthreads();
    int ks = ft >> 1, half = ft & 1;
#pragma unroll
    for (int i = 0; i < 16; ++i) {
      int tl = w * 16 + i;
      unsigned long long mask = __ballot(tile[lane][tl] != 0.0f);
      if (lane == 0) {
        unsigned lo = (unsigned)mask, hi = (unsigned)(mask >> 32);
        unsigned w0 = __builtin_amdgcn_perm(hi, lo, 0x05040100u); // j0,j1,j4,j5
        unsigned w1 = __builtin_amdgcn_perm(hi, lo, 0x07060302u); // j2,j3,j6,j7
        int col = n * TP + t0 + tl;
        unsigned char* g = Bg + ((size_t)ks * 8192 + col) * 16 + half * 4;
        *(unsigned*)(g) = w0;
        *(unsigned*)(g + 8) = w1;
      }
    }
  } else {
    int sb = bx - 12800;          // 0..255, 4 o-rows each
    int o0 = sb * 4;
#pragma unroll 5
    for (int it = 0; it < 25; ++it) {
      int e = it * 1024 + tid * 4;
      int row = e / 6400;
      int f = e - row * 6400;
      int o = o0 + row;
      float w4[4] = {0.f, 0.f, 0.f, 0.f};
      if (f < F1) {
        const f32x4 v = *(const f32x4*)(W + (size_t)o * F1 + f);
        w4[0] = v[0]; w4[1] = v[1]; w4[2] = v[2]; w4[3] = v[3];
      }
      char c0[4], c1[4];
#pragma unroll
      for (int j = 0; j < 4; ++j) {
        int wq = __float2int_rn(w4[j] * 32768.0f);
        int h0 = ((wq + 128) & 255) - 128;
        int h1 = (wq - h0) >> 8;
        c0[j] = (char)h0; c1[j] = (char)h1;
      }
      *(char4*)(H0 + (size_t)o * KP + f) = make_char4(c0[0], c0[1], c0[2], c0[3]);
      *(char4*)(H1 + (size_t)o * KP + f) = make_char4(c1[0], c1[1], c1[2], c1[3]);
    }
  }
}

// ============ K1: tactile dense -> psp -> spike =============================
__global__ void __launch_bounds__(512) k_tact(const float* __restrict__ xt,
                                              const float* __restrict__ Wt,
                                              float* __restrict__ s_tact) {
  __shared__ float atv[TP * 26];   // [t][o]
  int n = blockIdx.x >> 1, half = blockIdx.x & 1;
  int t = threadIdx.x;
  if (t < TT) {
    float acc[25];
#pragma unroll
    for (int o = 0; o < 25; ++o) acc[o] = 0.f;
    for (int f = 0; f < FT; ++f) {
      float x = xt[((size_t)n * FT + f) * TT + t];
#pragma unroll
      for (int o = 0; o < 25; ++o)
        acc[o] = fmaf(Wt[(half * 25 + o) * FT + f], x, acc[o]);
    }
#pragma unroll
    for (int o = 0; o < 25; ++o) atv[t * 26 + o] = acc[o];
  }
  __syncthreads();
  if (t < 25) {
    float p = 0.f, r = 0.f;
    float* op = s_tact + ((size_t)n * OT + half * 25 + t) * TT;
    for (int i = 0; i < TT; i += 10) {
      float u[10];
#pragma unroll
      for (int j = 0; j < 10; ++j) u[j] = atv[(i + j) * 26 + t];
#pragma unroll
      for (int j = 0; j < 10; ++j) {
        p = DSR * p + u[j];
        float v = p + r;
        bool s = (v >= THETA);
        r = DREF * (r - (s ? REFAMP : 0.f));
        op[i + j] = s ? 1.f : 0.f;
      }
    }
  }
}

// ============ K2: GEMM C = W * bits^T, 2-plane base-256, B in registers =====
// BM=128 BN=256 BK=128, 512 thr (8 waves 4wr x 2wc, wave tile 32x128),
// A planes dbuf LDS 64KB via global_load_lds, counted vmcnt(8) 2-deep,
// B bitmap loaded to regs (coalesced dwordx2), expanded by nibble-multiply.
__global__ void __launch_bounds__(512, 2) k_gemm(const char* __restrict__ H0,
                                                 const char* __restrict__ H1,
                                                 const unsigned char* __restrict__ Bg,
                                                 float* __restrict__ C) {
  __shared__ char A0[2][128 * 128];
  __shared__ char A1[2][128 * 128];
  int tid = threadIdx.x, bid = blockIdx.x;
  int gy = bid & 7, gx = bid >> 3;          // 8 gy (XCD-pinned) x 32 gx
  int wave = tid >> 6, lane = tid & 63;
  int wr = wave >> 1, wc = wave & 1;        // 4 x 2
  int l31 = lane & 31, h = lane >> 5;

  i32x16 acc0[4], acc1[4];
#pragma unroll
  for (int nn = 0; nn < 4; ++nn) { acc0[nn] = (i32x16)0; acc1[nn] = (i32x16)0; }

  // A staging: granule p = j*512+tid; row=p>>3; src slot = (p&7)^(row&7)
  size_t ga[2]; unsigned ldsa[2];
#pragma unroll
  for (int j = 0; j < 2; ++j) {
    int p = j * 512 + tid;
    int row = p >> 3;
    int src = (p & 7) ^ (row & 7);
    ga[j] = (size_t)(gy * 128 + row) * KP + src * 16;
    ldsa[j] = (unsigned)p * 16u;
  }
  // B lane pointers (per nn), stride per ks = 8192*16
  const unsigned char* bp[4];
#pragma unroll
  for (int nn = 0; nn < 4; ++nn)
    bp[nn] = Bg + ((size_t)(gx * 256 + wc * 128 + nn * 32 + l31) * 16) + h * 8;

  // A fragment offsets: row ra, logical granule kk*2+h, XOR-unswizzle
  int ra = wr * 32 + l31;
  int offA[4];
#pragma unroll
  for (int kk = 0; kk < 4; ++kk)
    offA[kk] = ra * 128 + (((kk * 2 + h) ^ (ra & 7)) * 16);

#define STAGE(ks, buf) do {                                       \
    size_t ko = (size_t)(ks) * 128;                               \
    GLL16(H0 + ga[0] + ko, (char*)&A0[buf][0] + ldsa[0]);         \
    GLL16(H0 + ga[1] + ko, (char*)&A0[buf][0] + ldsa[1]);         \
    GLL16(H1 + ga[0] + ko, (char*)&A1[buf][0] + ldsa[0]);         \
    GLL16(H1 + ga[1] + ko, (char*)&A1[buf][0] + ldsa[1]);         \
  } while (0)

#define LDB(ks, arr) do {                                         \
    _Pragma("unroll")                                             \
    for (int nn = 0; nn < 4; ++nn)                                \
      arr[nn] = *(const uint2*)(bp[nn] + (size_t)(ks) * 131072);  \
  } while (0)

#define BODY(ks, buf, bregs) do {                                               \
    if ((ks) == NKS - 1) { asm volatile("s_waitcnt vmcnt(0)" ::: "memory"); }   \
    else                 { asm volatile("s_waitcnt vmcnt(8)" ::: "memory"); }   \
    __builtin_amdgcn_sched_barrier(0);                                          \
    __builtin_amdgcn_s_barrier();                                               \
    __builtin_amdgcn_sched_barrier(0);                                          \
    _Pragma("unroll")                                                           \
    for (int kk = 0; kk < 4; ++kk) {                                            \
      i32x4 fa0 = *(const i32x4*)(&A0[buf][0] + offA[kk]);                      \
      i32x4 fa1 = *(const i32x4*)(&A1[buf][0] + offA[kk]);                      \
      i32x4 bv[4];                                                              \
      _Pragma("unroll")                                                         \
      for (int nn = 0; nn < 4; ++nn) {                                          \
        unsigned x = ((kk < 2) ? bregs[nn].x : bregs[nn].y) >> ((kk & 1) * 16); \
        x &= 0xFFFFu;                                                           \
        _Pragma("unroll")                                                       \
        for (int w = 0; w < 4; ++w) {                                           \
          unsigned nib = (x >> (4 * w)) & 0xFu;                                 \
          bv[nn][w] = (int)((nib * 0x00204081u) & 0x01010101u);                 \
        }                                                                       \
      }                                                                         \
      __builtin_amdgcn_s_setprio(1);                                            \
      _Pragma("unroll")                                                         \
      for (int nn = 0; nn < 4; ++nn) {                                          \
        acc0[nn] = __builtin_amdgcn_mfma_i32_32x32x32_i8(fa0, bv[nn], acc0[nn], 0, 0, 0); \
        acc1[nn] = __builtin_amdgcn_mfma_i32_32x32x32_i8(fa1, bv[nn], acc1[nn], 0, 0, 0); \
      }                                                                         \
      __builtin_amdgcn_s_setprio(0);                                            \
    }                                                                           \
    __builtin_amdgcn_s_barrier();                                               \
    __builtin_amdgcn_sched_barrier(0);                                          \
    if ((ks) + 2 < NKS) { STAGE((ks) + 2, buf); LDB((ks) + 2, bregs); }         \
  } while (0)

  uint2 bA[4], bB[4];
  STAGE(0, 0); LDB(0, bA);
  STAGE(1, 1); LDB(1, bB);

  for (int ks = 0; ks < NKS; ks += 2) {
    BODY(ks, 0, bA);
    BODY(ks + 1, 1, bB);
  }
#undef BODY
#undef LDB
#undef STAGE

  // C/D 32x32: col = lane&31, row = (reg&3) + 8*(reg>>2) + 4*h
#pragma unroll
  for (int nn = 0; nn < 4; ++nn) {
    int ob = gy * 128 + wr * 32;
    int cb = gx * 256 + wc * 128 + nn * 32 + l31;
#pragma unroll
    for (int reg = 0; reg < 16; ++reg) {
      int row = (reg & 3) + 8 * (reg >> 2) + 4 * h;
      int v = acc0[nn][reg] + (acc1[nn][reg] << 8);
      C[(size_t)(ob + row) * NC + cb] = (float)v * (1.0f / 32768.0f);
    }
  }
}

// ============ K3: psp+spike + fused partial Wv2 dot -> a2part ===============
__global__ void __launch_bounds__(256) k_spk1(const float* __restrict__ C,
                                              const float* __restrict__ Wv2,
                                              float* __restrict__ a2part) {
  __shared__ float tile[128 * 65];   // [t_local][ch]
  __shared__ char  spkb[128 * 68];   // [t_local][ch]
  __shared__ float w2s[O2][64];
  int og = blockIdx.x, n = blockIdx.y;
  int tid = threadIdx.x;
  for (int i = tid; i < O2 * 64; i += 256)
    w2s[i >> 6][i & 63] = Wv2[(i >> 6) * O1 + og * 64 + (i & 63)];
  float p = 0.f, r = 0.f;
  for (int tc = 0; tc < 4; ++tc) {
#pragma unroll
    for (int i = 0; i < 8; ++i) {
      int idx = i * 256 + tid;
      int row = idx >> 5, c4 = idx & 31;
      f32x4 v = *(const f32x4*)(C + (size_t)(og * 64 + row) * NC + n * TP + tc * 128 + c4 * 4);
#pragma unroll
      for (int j = 0; j < 4; ++j) tile[(c4 * 4 + j) * 65 + row] = v[j];
    }
    __syncthreads();
    if (tid < 64) {
      float pp = p, rr = r;
      for (int i = 0; i < 128; i += 8) {
        float u[8];
#pragma unroll
        for (int j = 0; j < 8; ++j) u[j] = tile[(i + j) * 65 + tid];
#pragma unroll
        for (int j = 0; j < 8; ++j) {
          pp = DSR * pp + u[j];
          float v = pp + rr;
          bool s = (v >= THETA);
          rr = DREF * (rr - (s ? REFAMP : 0.f));
          spkb[(i + j) * 68 + tid] = s ? (char)1 : (char)0;
        }
      }
      p = pp; r = rr;
    }
    __syncthreads();
    if (tid < 128) {
      float acc[O2];
#pragma unroll
      for (int o = 0; o < O2; ++o) acc[o] = 0.f;
      for (int row = 0; row < 64; ++row) {
        float s = (spkb[tid * 68 + row] != 0) ? 1.f : 0.f;
#pragma unroll
        for (int o = 0; o < O2; ++o) acc[o] = fmaf(w2s[o][row], s, acc[o]);
      }
      int tglob = tc * 128 + tid;
#pragma unroll
      for (int o = 0; o < O2; ++o)
        a2part[(((size_t)og * NB + n) * O2 + o) * TP + tglob] = acc[o];
    }
    __syncthreads();
  }
}

// ============ K4: reduce a2part -> psp+spike -> Wf -> psp+spike -> out ======
__global__ void __launch_bounds__(512) k_finish(const float* __restrict__ a2part,
                                                const float* __restrict__ s_tact,
                                                const float* __restrict__ Wf,
                                                float* __restrict__ out) {
  __shared__ float u2[TP * 12];
  __shared__ float af[TP * 21];
  int n = blockIdx.x, t = threadIdx.x;
#pragma unroll
  for (int o = 0; o < O2; ++o) {
    float s = 0.f;
#pragma unroll
    for (int og = 0; og < NB; ++og)
      s += a2part[(((size_t)og * NB + n) * O2 + o) * TP + t];
    u2[t * 12 + o] = s;
  }
  __syncthreads();
  if (t < O2) {
    float p = 0.f, r = 0.f;
    for (int i = 0; i < TT; i += 10) {
      float u[10];
#pragma unroll
      for (int j = 0; j < 10; ++j) u[j] = u2[(i + j) * 12 + t];
#pragma unroll
      for (int j = 0; j < 10; ++j) {
        p = DSR * p + u[j];
        float v = p + r;
        bool s = (v >= THETA);
        r = DREF * (r - (s ? REFAMP : 0.f));
        u2[(i + j) * 12 + t] = s ? 1.f : 0.f;
      }
    }
  }
  __syncthreads();
  if (t < TT) {
    float acc[OF];
#pragma unroll
    for (int o = 0; o < OF; ++o) acc[o] = 0.f;
    for (int f = 0; f < OT; ++f) {
      float s = s_tact[((size_t)n * OT + f) * TT + t];
#pragma unroll
      for (int o = 0; o < OF; ++o) acc[o] = fmaf(Wf[o * 60 + f], s, acc[o]);
    }
#pragma unroll
    for (int f = 0; f < O2; ++f) {
      float s = u2[t * 12 + f];
#pragma unroll
      for (int o = 0; o < OF; ++o) acc[o] = fmaf(Wf[o * 60 + OT + f], s, acc[o]);
    }
#pragma unroll
    for (int o = 0; o < OF; ++o) af[t * 21 + o] = acc[o];
  }
  __syncthreads();
  if (t < OF) {
    float p = 0.f, r = 0.f;
    float* op = out + ((size_t)n * OF + t) * TT;
    for (int i = 0; i < TT; i += 10) {
      float u[10];
#pragma unroll
      for (int j = 0; j < 10; ++j) u[j] = af[(i + j) * 21 + t];
#pragma unroll
      for (int j = 0; j < 10; ++j) {
        p = DSR * p + u[j];
        float v = p + r;
        bool s = (v >= THETA);
        r = DREF * (r - (s ? REFAMP : 0.f));
        op[i + j] = s ? 1.f : 0.f;
      }
    }
  }
}

extern "C" void kernel_launch(void* const* d_in, const int* in_sizes, int n_in,
                              void* d_out, int out_size, void* d_ws, size_t ws_size,
                              hipStream_t stream) {
  (void)in_sizes; (void)n_in; (void)out_size; (void)ws_size;
  const float* xt  = (const float*)d_in[0];
  const float* xv  = (const float*)d_in[1];
  const float* Wt  = (const float*)d_in[2];
  const float* Wv1 = (const float*)d_in[3];
  const float* Wv2 = (const float*)d_in[4];
  const float* Wf  = (const float*)d_in[5];
  float* out = (float*)d_out;

  char* ws = (char*)d_ws;
  size_t off = 0;
  auto carve = [&](size_t bytes) {
    char* p = ws + off;
    off += (bytes + 255) & ~(size_t)255;
    return p;
  };
  char*          H0    = carve((size_t)O1 * KP);
  char*          H1    = carve((size_t)O1 * KP);
  unsigned char* Bg    = (unsigned char*)carve((size_t)NKS * 8192 * 16);
  float*         a1    = (float*)carve((size_t)O1 * NC * 4);
  float*         stact = (float*)carve((size_t)NB * OT * TT * 4);
  float*         a2p   = (float*)carve((size_t)NB * NB * O2 * TP * 4);

  k_prep<<<dim3(13056), dim3(256), 0, stream>>>(xv, Wv1, Bg, H0, H1);
  k_tact<<<dim3(NB * 2), dim3(512), 0, stream>>>(xt, Wt, stact);
  k_gemm<<<dim3(256), dim3(512), 0, stream>>>(H0, H1, Bg, a1);
  k_spk1<<<dim3(16, NB), dim3(256), 0, stream>>>(a1, Wv2, a2p);
  k_finish<<<dim3(NB), dim3(512), 0, stream>>>(a2p, stact, Wf, out);
}

// Round 9
// 301.630 us; speedup vs baseline: 2.9417x; 1.0919x over previous
//
#include <hip/hip_runtime.h>
#include <stdint.h>

#define DSR   0.90483741803595952f   // exp(-1/10)
#define DREF  0.36787944117144233f   // exp(-1)
#define THETA 10.0f
#define REFAMP 20.0f                 // SCALE_REF * THETA

#define NB 16
#define TT 500
#define TP 512
#define F1 6300
#define KP 6400      // K padded (multiple of 128)
#define NKS 50       // KP/128
#define O1 1024
#define NC 8192      // NB * TP columns
#define FT 156
#define OT 50
#define O2 10
#define OF 20

typedef __attribute__((ext_vector_type(4)))  float f32x4;
typedef __attribute__((ext_vector_type(4)))  int   i32x4;
typedef __attribute__((ext_vector_type(16))) int   i32x16;

#define GLL16(g, l) __builtin_amdgcn_global_load_lds( \
    (const __attribute__((address_space(1))) void*)(g), \
    (__attribute__((address_space(3))) void*)(l), 16, 0, 0)

// ============ K0: fused prep =================================================
// blocks [0,1600): (ft, n) — xv -> bitmap Bg[ks(50)][col(8192)] 16B granules.
//   f32x4 coalesced loads -> byte tile -> ballot transpose (R8 byte format).
// blocks [1600,1856): Wv1 -> 2 signed base-256 i8 planes, w*2^15 = h0+256*h1.
__global__ void __launch_bounds__(256) k_prep(const float* __restrict__ xv,
                                              const float* __restrict__ W,
                                              unsigned char* __restrict__ Bg,
                                              char* __restrict__ H0,
                                              char* __restrict__ H1) {
  __shared__ unsigned char tb[64][68];   // 4.4 KB, ballot-read conflict ~2-way
  int bx = blockIdx.x, tid = threadIdx.x;
  if (bx < 1600) {
    int ft = bx % 100, n = bx / 100;
    int f0 = ft * 64;
    int lane = tid & 63, w = tid >> 6;
    int ks = ft >> 1, half = ft & 1;
    for (int tc = 0; tc < 8; ++tc) {
      int t0 = tc * 64;
      // load 64 f-rows x 64 t as f32x4 (16B/lane, coalesced), convert to bytes
#pragma unroll
      for (int it = 0; it < 4; ++it) {
        int idx = it * 256 + tid;         // 0..1023
        int row = idx >> 4, c4 = idx & 15;
        int f = f0 + row, t = t0 + c4 * 4;
        uchar4 b = make_uchar4(0, 0, 0, 0);
        if (f < F1) {
          if (t + 3 < TT) {
            f32x4 v = *(const f32x4*)(xv + ((size_t)n * F1 + f) * TT + t);
            b.x = (v[0] != 0.f); b.y = (v[1] != 0.f);
            b.z = (v[2] != 0.f); b.w = (v[3] != 0.f);
          } else {
#pragma unroll
            for (int j = 0; j < 4; ++j)
              if (t + j < TT) {
                float v = xv[((size_t)n * F1 + f) * TT + t + j];
                ((unsigned char*)&b)[j] = (v != 0.f);
              }
          }
        }
        *(uchar4*)&tb[row][c4 * 4] = b;
      }
      __syncthreads();
      // ballot transpose: wave w handles t-locals w*16..w*16+15
#pragma unroll
      for (int i = 0; i < 16; ++i) {
        int tl = w * 16 + i;
        unsigned long long mask = __ballot(tb[lane][tl] != 0);
        if (lane == 0) {
          unsigned lo = (unsigned)mask, hi = (unsigned)(mask >> 32);
          unsigned w0 = __builtin_amdgcn_perm(hi, lo, 0x05040100u); // j0,j1,j4,j5
          unsigned w1 = __builtin_amdgcn_perm(hi, lo, 0x07060302u); // j2,j3,j6,j7
          int col = n * TP + t0 + tl;
          unsigned char* g = Bg + ((size_t)ks * 8192 + col) * 16 + half * 4;
          *(unsigned*)(g) = w0;
          *(unsigned*)(g + 8) = w1;
        }
      }
      __syncthreads();
    }
  } else {
    int sb = bx - 1600;           // 0..255, 4 o-rows each
    int o0 = sb * 4;
#pragma unroll 5
    for (int it = 0; it < 25; ++it) {
      int e = it * 1024 + tid * 4;
      int row = e / 6400;
      int f = e - row * 6400;
      int o = o0 + row;
      float w4[4] = {0.f, 0.f, 0.f, 0.f};
      if (f < F1) {
        const f32x4 v = *(const f32x4*)(W + (size_t)o * F1 + f);
        w4[0] = v[0]; w4[1] = v[1]; w4[2] = v[2]; w4[3] = v[3];
      }
      char c0[4], c1[4];
#pragma unroll
      for (int j = 0; j < 4; ++j) {
        int wq = __float2int_rn(w4[j] * 32768.0f);
        int h0 = ((wq + 128) & 255) - 128;
        int h1 = (wq - h0) >> 8;
        c0[j] = (char)h0; c1[j] = (char)h1;
      }
      *(char4*)(H0 + (size_t)o * KP + f) = make_char4(c0[0], c0[1], c0[2], c0[3]);
      *(char4*)(H1 + (size_t)o * KP + f) = make_char4(c1[0], c1[1], c1[2], c1[3]);
    }
  }
}

// ============ K1: tactile dense -> psp -> spike =============================
__global__ void __launch_bounds__(512) k_tact(const float* __restrict__ xt,
                                              const float* __restrict__ Wt,
                                              float* __restrict__ s_tact) {
  __shared__ float atv[TP * 26];   // [t][o]
  int n = blockIdx.x >> 1, half = blockIdx.x & 1;
  int t = threadIdx.x;
  if (t < TT) {
    float acc[25];
#pragma unroll
    for (int o = 0; o < 25; ++o) acc[o] = 0.f;
    for (int f = 0; f < FT; ++f) {
      float x = xt[((size_t)n * FT + f) * TT + t];
#pragma unroll
      for (int o = 0; o < 25; ++o)
        acc[o] = fmaf(Wt[(half * 25 + o) * FT + f], x, acc[o]);
    }
#pragma unroll
    for (int o = 0; o < 25; ++o) atv[t * 26 + o] = acc[o];
  }
  __syncthreads();
  if (t < 25) {
    float p = 0.f, r = 0.f;
    float* op = s_tact + ((size_t)n * OT + half * 25 + t) * TT;
    for (int i = 0; i < TT; i += 10) {
      float u[10];
#pragma unroll
      for (int j = 0; j < 10; ++j) u[j] = atv[(i + j) * 26 + t];
#pragma unroll
      for (int j = 0; j < 10; ++j) {
        p = DSR * p + u[j];
        float v = p + r;
        bool s = (v >= THETA);
        r = DREF * (r - (s ? REFAMP : 0.f));
        op[i + j] = s ? 1.f : 0.f;
      }
    }
  }
}

// ============ K2: GEMM C = W * bits^T, 2-plane base-256, B in registers =====
// BM=128 BN=256 BK=128, 512 thr (8 waves 4wr x 2wc, wave tile 32x128),
// A planes dbuf LDS 64KB via global_load_lds, counted vmcnt(8) 2-deep,
// B bitmap loaded to regs (coalesced dwordx2), expanded by nibble-multiply.
__global__ void __launch_bounds__(512, 2) k_gemm(const char* __restrict__ H0,
                                                 const char* __restrict__ H1,
                                                 const unsigned char* __restrict__ Bg,
                                                 float* __restrict__ C) {
  __shared__ char A0[2][128 * 128];
  __shared__ char A1[2][128 * 128];
  int tid = threadIdx.x, bid = blockIdx.x;
  int gy = bid & 7, gx = bid >> 3;          // 8 gy (XCD-pinned) x 32 gx
  int wave = tid >> 6, lane = tid & 63;
  int wr = wave >> 1, wc = wave & 1;        // 4 x 2
  int l31 = lane & 31, h = lane >> 5;

  i32x16 acc0[4], acc1[4];
#pragma unroll
  for (int nn = 0; nn < 4; ++nn) { acc0[nn] = (i32x16)0; acc1[nn] = (i32x16)0; }

  // A staging: granule p = j*512+tid; row=p>>3; src slot = (p&7)^(row&7)
  size_t ga[2]; unsigned ldsa[2];
#pragma unroll
  for (int j = 0; j < 2; ++j) {
    int p = j * 512 + tid;
    int row = p >> 3;
    int src = (p & 7) ^ (row & 7);
    ga[j] = (size_t)(gy * 128 + row) * KP + src * 16;
    ldsa[j] = (unsigned)p * 16u;
  }
  // B lane pointers (per nn), stride per ks = 8192*16
  const unsigned char* bp[4];
#pragma unroll
  for (int nn = 0; nn < 4; ++nn)
    bp[nn] = Bg + ((size_t)(gx * 256 + wc * 128 + nn * 32 + l31) * 16) + h * 8;

  // A fragment offsets: row ra, logical granule kk*2+h, XOR-unswizzle
  int ra = wr * 32 + l31;
  int offA[4];
#pragma unroll
  for (int kk = 0; kk < 4; ++kk)
    offA[kk] = ra * 128 + (((kk * 2 + h) ^ (ra & 7)) * 16);

#define STAGE(ks, buf) do {                                       \
    size_t ko = (size_t)(ks) * 128;                               \
    GLL16(H0 + ga[0] + ko, (char*)&A0[buf][0] + ldsa[0]);         \
    GLL16(H0 + ga[1] + ko, (char*)&A0[buf][0] + ldsa[1]);         \
    GLL16(H1 + ga[0] + ko, (char*)&A1[buf][0] + ldsa[0]);         \
    GLL16(H1 + ga[1] + ko, (char*)&A1[buf][0] + ldsa[1]);         \
  } while (0)

#define LDB(ks, arr) do {                                         \
    _Pragma("unroll")                                             \
    for (int nn = 0; nn < 4; ++nn)                                \
      arr[nn] = *(const uint2*)(bp[nn] + (size_t)(ks) * 131072);  \
  } while (0)

#define BODY(ks, buf, bregs) do {                                               \
    if ((ks) == NKS - 1) { asm volatile("s_waitcnt vmcnt(0)" ::: "memory"); }   \
    else                 { asm volatile("s_waitcnt vmcnt(8)" ::: "memory"); }   \
    __builtin_amdgcn_sched_barrier(0);                                          \
    __builtin_amdgcn_s_barrier();                                               \
    __builtin_amdgcn_sched_barrier(0);                                          \
    _Pragma("unroll")                                                           \
    for (int kk = 0; kk < 4; ++kk) {                                            \
      i32x4 fa0 = *(const i32x4*)(&A0[buf][0] + offA[kk]);                      \
      i32x4 fa1 = *(const i32x4*)(&A1[buf][0] + offA[kk]);                      \
      i32x4 bv[4];                                                              \
      _Pragma("unroll")                                                         \
      for (int nn = 0; nn < 4; ++nn) {                                          \
        unsigned x = ((kk < 2) ? bregs[nn].x : bregs[nn].y) >> ((kk & 1) * 16); \
        x &= 0xFFFFu;                                                           \
        _Pragma("unroll")                                                       \
        for (int w = 0; w < 4; ++w) {                                           \
          unsigned nib = (x >> (4 * w)) & 0xFu;                                 \
          bv[nn][w] = (int)((nib * 0x00204081u) & 0x01010101u);                 \
        }                                                                       \
      }                                                                         \
      __builtin_amdgcn_s_setprio(1);                                            \
      _Pragma("unroll")                                                         \
      for (int nn = 0; nn < 4; ++nn) {                                          \
        acc0[nn] = __builtin_amdgcn_mfma_i32_32x32x32_i8(fa0, bv[nn], acc0[nn], 0, 0, 0); \
        acc1[nn] = __builtin_amdgcn_mfma_i32_32x32x32_i8(fa1, bv[nn], acc1[nn], 0, 0, 0); \
      }                                                                         \
      __builtin_amdgcn_s_setprio(0);                                            \
    }                                                                           \
    __builtin_amdgcn_s_barrier();                                               \
    __builtin_amdgcn_sched_barrier(0);                                          \
    if ((ks) + 2 < NKS) { STAGE((ks) + 2, buf); LDB((ks) + 2, bregs); }         \
  } while (0)

  uint2 bA[4], bB[4];
  STAGE(0, 0); LDB(0, bA);
  STAGE(1, 1); LDB(1, bB);

  for (int ks = 0; ks < NKS; ks += 2) {
    BODY(ks, 0, bA);
    BODY(ks + 1, 1, bB);
  }
#undef BODY
#undef LDB
#undef STAGE

  // C/D 32x32: col = lane&31, row = (reg&3) + 8*(reg>>2) + 4*h
#pragma unroll
  for (int nn = 0; nn < 4; ++nn) {
    int ob = gy * 128 + wr * 32;
    int cb = gx * 256 + wc * 128 + nn * 32 + l31;
#pragma unroll
    for (int reg = 0; reg < 16; ++reg) {
      int row = (reg & 3) + 8 * (reg >> 2) + 4 * h;
      int v = acc0[nn][reg] + (acc1[nn][reg] << 8);
      C[(size_t)(ob + row) * NC + cb] = (float)v * (1.0f / 32768.0f);
    }
  }
}

// ============ K3: psp+spike + fused partial Wv2 dot -> a2part ===============
__global__ void __launch_bounds__(256) k_spk1(const float* __restrict__ C,
                                              const float* __restrict__ Wv2,
                                              float* __restrict__ a2part) {
  __shared__ float tile[128 * 65];   // [t_local][ch]
  __shared__ char  spkb[128 * 68];   // [t_local][ch]
  __shared__ float w2s[O2][64];
  int og = blockIdx.x, n = blockIdx.y;
  int tid = threadIdx.x;
  for (int i = tid; i < O2 * 64; i += 256)
    w2s[i >> 6][i & 63] = Wv2[(i >> 6) * O1 + og * 64 + (i & 63)];
  float p = 0.f, r = 0.f;
  for (int tc = 0; tc < 4; ++tc) {
#pragma unroll
    for (int i = 0; i < 8; ++i) {
      int idx = i * 256 + tid;
      int row = idx >> 5, c4 = idx & 31;
      f32x4 v = *(const f32x4*)(C + (size_t)(og * 64 + row) * NC + n * TP + tc * 128 + c4 * 4);
#pragma unroll
      for (int j = 0; j < 4; ++j) tile[(c4 * 4 + j) * 65 + row] = v[j];
    }
    __syncthreads();
    if (tid < 64) {
      float pp = p, rr = r;
      for (int i = 0; i < 128; i += 8) {
        float u[8];
#pragma unroll
        for (int j = 0; j < 8; ++j) u[j] = tile[(i + j) * 65 + tid];
#pragma unroll
        for (int j = 0; j < 8; ++j) {
          pp = DSR * pp + u[j];
          float v = pp + rr;
          bool s = (v >= THETA);
          rr = DREF * (rr - (s ? REFAMP : 0.f));
          spkb[(i + j) * 68 + tid] = s ? (char)1 : (char)0;
        }
      }
      p = pp; r = rr;
    }
    __syncthreads();
    if (tid < 128) {
      float acc[O2];
#pragma unroll
      for (int o = 0; o < O2; ++o) acc[o] = 0.f;
      for (int row = 0; row < 64; ++row) {
        float s = (spkb[tid * 68 + row] != 0) ? 1.f : 0.f;
#pragma unroll
        for (int o = 0; o < O2; ++o) acc[o] = fmaf(w2s[o][row], s, acc[o]);
      }
      int tglob = tc * 128 + tid;
#pragma unroll
      for (int o = 0; o < O2; ++o)
        a2part[(((size_t)og * NB + n) * O2 + o) * TP + tglob] = acc[o];
    }
    __syncthreads();
  }
}

// ============ K4: reduce a2part -> psp+spike -> Wf -> psp+spike -> out ======
__global__ void __launch_bounds__(512) k_finish(const float* __restrict__ a2part,
                                                const float* __restrict__ s_tact,
                                                const float* __restrict__ Wf,
                                                float* __restrict__ out) {
  __shared__ float u2[TP * 12];
  __shared__ float af[TP * 21];
  int n = blockIdx.x, t = threadIdx.x;
#pragma unroll
  for (int o = 0; o < O2; ++o) {
    float s = 0.f;
#pragma unroll
    for (int og = 0; og < NB; ++og)
      s += a2part[(((size_t)og * NB + n) * O2 + o) * TP + t];
    u2[t * 12 + o] = s;
  }
  __syncthreads();
  if (t < O2) {
    float p = 0.f, r = 0.f;
    for (int i = 0; i < TT; i += 10) {
      float u[10];
#pragma unroll
      for (int j = 0; j < 10; ++j) u[j] = u2[(i + j) * 12 + t];
#pragma unroll
      for (int j = 0; j < 10; ++j) {
        p = DSR * p + u[j];
        float v = p + r;
        bool s = (v >= THETA);
        r = DREF * (r - (s ? REFAMP : 0.f));
        u2[(i + j) * 12 + t] = s ? 1.f : 0.f;
      }
    }
  }
  __syncthreads();
  if (t < TT) {
    float acc[OF];
#pragma unroll
    for (int o = 0; o < OF; ++o) acc[o] = 0.f;
    for (int f = 0; f < OT; ++f) {
      float s = s_tact[((size_t)n * OT + f) * TT + t];
#pragma unroll
      for (int o = 0; o < OF; ++o) acc[o] = fmaf(Wf[o * 60 + f], s, acc[o]);
    }
#pragma unroll
    for (int f = 0; f < O2; ++f) {
      float s = u2[t * 12 + f];
#pragma unroll
      for (int o = 0; o < OF; ++o) acc[o] = fmaf(Wf[o * 60 + OT + f], s, acc[o]);
    }
#pragma unroll
    for (int o = 0; o < OF; ++o) af[t * 21 + o] = acc[o];
  }
  __syncthreads();
  if (t < OF) {
    float p = 0.f, r = 0.f;
    float* op = out + ((size_t)n * OF + t) * TT;
    for (int i = 0; i < TT; i += 10) {
      float u[10];
#pragma unroll
      for (int j = 0; j < 10; ++j) u[j] = af[(i + j) * 21 + t];
#pragma unroll
      for (int j = 0; j < 10; ++j) {
        p = DSR * p + u[j];
        float v = p + r;
        bool s = (v >= THETA);
        r = DREF * (r - (s ? REFAMP : 0.f));
        op[i + j] = s ? 1.f : 0.f;
      }
    }
  }
}

extern "C" void kernel_launch(void* const* d_in, const int* in_sizes, int n_in,
                              void* d_out, int out_size, void* d_ws, size_t ws_size,
                              hipStream_t stream) {
  (void)in_sizes; (void)n_in; (void)out_size; (void)ws_size;
  const float* xt  = (const float*)d_in[0];
  const float* xv  = (const float*)d_in[1];
  const float* Wt  = (const float*)d_in[2];
  const float* Wv1 = (const float*)d_in[3];
  const float* Wv2 = (const float*)d_in[4];
  const float* Wf  = (const float*)d_in[5];
  float* out = (float*)d_out;

  char* ws = (char*)d_ws;
  size_t off = 0;
  auto carve = [&](size_t bytes) {
    char* p = ws + off;
    off += (bytes + 255) & ~(size_t)255;
    return p;
  };
  char*          H0    = carve((size_t)O1 * KP);
  char*          H1    = carve((size_t)O1 * KP);
  unsigned char* Bg    = (unsigned char*)carve((size_t)NKS * 8192 * 16);
  float*         a1    = (float*)carve((size_t)O1 * NC * 4);
  float*         stact = (float*)carve((size_t)NB * OT * TT * 4);
  float*         a2p   = (float*)carve((size_t)NB * NB * O2 * TP * 4);

  k_prep<<<dim3(1856), dim3(256), 0, stream>>>(xv, Wv1, Bg, H0, H1);
  k_tact<<<dim3(NB * 2), dim3(512), 0, stream>>>(xt, Wt, stact);
  k_gemm<<<dim3(256), dim3(512), 0, stream>>>(H0, H1, Bg, a1);
  k_spk1<<<dim3(16, NB), dim3(256), 0, stream>>>(a1, Wv2, a2p);
  k_finish<<<dim3(NB), dim3(512), 0, stream>>>(a2p, stact, Wf, out);
}

// Round 10
// 276.116 us; speedup vs baseline: 3.2135x; 1.0924x over previous
//
#include <hip/hip_runtime.h>
#include <stdint.h>

#define DSR   0.90483741803595952f   // exp(-1/10)
#define DREF  0.36787944117144233f   // exp(-1)
#define THETA 10.0f
#define REFAMP 20.0f                 // SCALE_REF * THETA

#define NB 16
#define TT 500
#define TP 512
#define F1 6300
#define KP 6400      // K padded (multiple of 128)
#define NKS 50       // KP/128
#define O1 1024
#define NC 8192      // NB * TP columns
#define FT 156
#define OT 50
#define O2 10
#define OF 20

typedef __attribute__((ext_vector_type(4)))  float f32x4;
typedef __attribute__((ext_vector_type(4)))  int   i32x4;
typedef __attribute__((ext_vector_type(16))) int   i32x16;

#define GLL16(g, l) __builtin_amdgcn_global_load_lds( \
    (const __attribute__((address_space(1))) void*)(g), \
    (__attribute__((address_space(3))) void*)(l), 16, 0, 0)

// ============ K0: fused prep (bitmap | weight planes | tactile) =============
// blocks [0,1600): (ft,n) xv -> bitmap Bg[ks][col] 16B granules (R8 format)
// blocks [1600,1856): Wv1 -> 2 signed base-256 i8 planes (4 o-rows each)
// blocks [1856,1888): tactile dense -> psp -> spike -> s_tact
__global__ void __launch_bounds__(512) k_prep(const float* __restrict__ xv,
                                              const float* __restrict__ W,
                                              const float* __restrict__ xt,
                                              const float* __restrict__ Wt,
                                              unsigned char* __restrict__ Bg,
                                              char* __restrict__ H0,
                                              char* __restrict__ H1,
                                              float* __restrict__ s_tact) {
  __shared__ float smem[TP * 26];   // 53 KB; aliased by bitmap path
  int bx = blockIdx.x, tid = threadIdx.x;
  if (bx < 1600) {
    unsigned char (*tb)[68] = (unsigned char (*)[68])smem;   // 64x68 bytes
    int ft = bx % 100, n = bx / 100;
    int f0 = ft * 64;
    int lane = tid & 63, w = tid >> 6;    // 8 waves
    int ks = ft >> 1, half = ft & 1;
    for (int tc = 0; tc < 8; ++tc) {
      int t0 = tc * 64;
#pragma unroll
      for (int it = 0; it < 2; ++it) {
        int idx = it * 512 + tid;         // 0..1023
        int row = idx >> 4, c4 = idx & 15;
        int f = f0 + row, t = t0 + c4 * 4;
        uchar4 b = make_uchar4(0, 0, 0, 0);
        if (f < F1) {
          if (t + 3 < TT) {
            f32x4 v = *(const f32x4*)(xv + ((size_t)n * F1 + f) * TT + t);
            b.x = (v[0] != 0.f); b.y = (v[1] != 0.f);
            b.z = (v[2] != 0.f); b.w = (v[3] != 0.f);
          } else {
#pragma unroll
            for (int j = 0; j < 4; ++j)
              if (t + j < TT) {
                float v = xv[((size_t)n * F1 + f) * TT + t + j];
                ((unsigned char*)&b)[j] = (v != 0.f);
              }
          }
        }
        *(uchar4*)&tb[row][c4 * 4] = b;
      }
      __syncthreads();
#pragma unroll
      for (int i = 0; i < 8; ++i) {
        int tl = w * 8 + i;
        unsigned long long mask = __ballot(tb[lane][tl] != 0);
        if (lane == 0) {
          unsigned lo = (unsigned)mask, hi = (unsigned)(mask >> 32);
          unsigned w0 = __builtin_amdgcn_perm(hi, lo, 0x05040100u);
          unsigned w1 = __builtin_amdgcn_perm(hi, lo, 0x07060302u);
          int col = n * TP + t0 + tl;
          unsigned char* g = Bg + ((size_t)ks * 8192 + col) * 16 + half * 4;
          *(unsigned*)(g) = w0;
          *(unsigned*)(g + 8) = w1;
        }
      }
      __syncthreads();
    }
  } else if (bx < 1856) {
    int sb = bx - 1600;           // 0..255, 4 o-rows each
    int o0 = sb * 4;
#pragma unroll
    for (int it = 0; it < 13; ++it) {
      int e = it * 2048 + tid * 4;
      if (e < 25600) {
        int row = e / 6400;
        int f = e - row * 6400;
        int o = o0 + row;
        float w4[4] = {0.f, 0.f, 0.f, 0.f};
        if (f < F1) {
          const f32x4 v = *(const f32x4*)(W + (size_t)o * F1 + f);
          w4[0] = v[0]; w4[1] = v[1]; w4[2] = v[2]; w4[3] = v[3];
        }
        char c0[4], c1[4];
#pragma unroll
        for (int j = 0; j < 4; ++j) {
          int wq = __float2int_rn(w4[j] * 32768.0f);
          int h0 = ((wq + 128) & 255) - 128;
          int h1 = (wq - h0) >> 8;
          c0[j] = (char)h0; c1[j] = (char)h1;
        }
        *(char4*)(H0 + (size_t)o * KP + f) = make_char4(c0[0], c0[1], c0[2], c0[3]);
        *(char4*)(H1 + (size_t)o * KP + f) = make_char4(c1[0], c1[1], c1[2], c1[3]);
      }
    }
  } else {
    // tactile: block = (n, half of 25 o's)
    float* atv = smem;            // [t][o] pad 26
    int blk = bx - 1856;
    int n = blk >> 1, half = blk & 1;
    int t = tid;
    if (t < TT) {
      float acc[25];
#pragma unroll
      for (int o = 0; o < 25; ++o) acc[o] = 0.f;
      for (int f = 0; f < FT; ++f) {
        float x = xt[((size_t)n * FT + f) * TT + t];
#pragma unroll
        for (int o = 0; o < 25; ++o)
          acc[o] = fmaf(Wt[(half * 25 + o) * FT + f], x, acc[o]);
      }
#pragma unroll
      for (int o = 0; o < 25; ++o) atv[t * 26 + o] = acc[o];
    }
    __syncthreads();
    if (t < 25) {
      float p = 0.f, r = 0.f;
      float* op = s_tact + ((size_t)n * OT + half * 25 + t) * TT;
      for (int i = 0; i < TT; i += 10) {
        float u[10];
#pragma unroll
        for (int j = 0; j < 10; ++j) u[j] = atv[(i + j) * 26 + t];
#pragma unroll
        for (int j = 0; j < 10; ++j) {
          p = DSR * p + u[j];
          float v = p + r;
          bool s = (v >= THETA);
          r = DREF * (r - (s ? REFAMP : 0.f));
          op[i + j] = s ? 1.f : 0.f;
        }
      }
    }
  }
}

// ============ K2: GEMM C = W * bits^T, 2-plane base-256, B in registers =====
// BM=128 BN=128 BK=128, 512 thr (8 waves 4wr x 2wc, wave tile 32x64),
// grid 512 = 2 blocks/CU (cross-block overlap hides barrier drains),
// A planes dbuf LDS 64KB via global_load_lds, counted vmcnt(6) 2-deep,
// B bitmap loaded to regs (coalesced dwordx2), expanded by nibble-multiply.
__global__ void __launch_bounds__(512, 4) k_gemm(const char* __restrict__ H0,
                                                 const char* __restrict__ H1,
                                                 const unsigned char* __restrict__ Bg,
                                                 float* __restrict__ C) {
  __shared__ char A0[2][128 * 128];
  __shared__ char A1[2][128 * 128];
  int tid = threadIdx.x, bid = blockIdx.x;
  int gy = bid & 7, gx = bid >> 3;          // 8 gy (XCD-pinned) x 64 gx
  int wave = tid >> 6, lane = tid & 63;
  int wr = wave >> 1, wc = wave & 1;        // 4 x 2, wave tile 32x64
  int l31 = lane & 31, h = lane >> 5;

  i32x16 acc0[2], acc1[2];
#pragma unroll
  for (int nn = 0; nn < 2; ++nn) { acc0[nn] = (i32x16)0; acc1[nn] = (i32x16)0; }

  // A staging: granule p = j*512+tid; row=p>>3; src slot = (p&7)^(row&7)
  size_t ga[2]; unsigned ldsa[2];
#pragma unroll
  for (int j = 0; j < 2; ++j) {
    int p = j * 512 + tid;
    int row = p >> 3;
    int src = (p & 7) ^ (row & 7);
    ga[j] = (size_t)(gy * 128 + row) * KP + src * 16;
    ldsa[j] = (unsigned)p * 16u;
  }
  // B lane pointers (per nn), stride per ks = 8192*16
  const unsigned char* bp[2];
#pragma unroll
  for (int nn = 0; nn < 2; ++nn)
    bp[nn] = Bg + ((size_t)(gx * 128 + wc * 64 + nn * 32 + l31) * 16) + h * 8;

  // A fragment offsets: row ra, logical granule kk*2+h, XOR-unswizzle
  int ra = wr * 32 + l31;
  int offA[4];
#pragma unroll
  for (int kk = 0; kk < 4; ++kk)
    offA[kk] = ra * 128 + (((kk * 2 + h) ^ (ra & 7)) * 16);

#define STAGE(ks, buf) do {                                       \
    size_t ko = (size_t)(ks) * 128;                               \
    GLL16(H0 + ga[0] + ko, (char*)&A0[buf][0] + ldsa[0]);         \
    GLL16(H0 + ga[1] + ko, (char*)&A0[buf][0] + ldsa[1]);         \
    GLL16(H1 + ga[0] + ko, (char*)&A1[buf][0] + ldsa[0]);         \
    GLL16(H1 + ga[1] + ko, (char*)&A1[buf][0] + ldsa[1]);         \
  } while (0)

#define LDB(ks, arr) do {                                         \
    _Pragma("unroll")                                             \
    for (int nn = 0; nn < 2; ++nn)                                \
      arr[nn] = *(const uint2*)(bp[nn] + (size_t)(ks) * 131072);  \
  } while (0)

#define BODY(ks, buf, bregs) do {                                               \
    if ((ks) == NKS - 1) { asm volatile("s_waitcnt vmcnt(0)" ::: "memory"); }   \
    else                 { asm volatile("s_waitcnt vmcnt(6)" ::: "memory"); }   \
    __builtin_amdgcn_sched_barrier(0);                                          \
    __builtin_amdgcn_s_barrier();                                               \
    __builtin_amdgcn_sched_barrier(0);                                          \
    _Pragma("unroll")                                                           \
    for (int kk = 0; kk < 4; ++kk) {                                            \
      i32x4 fa0 = *(const i32x4*)(&A0[buf][0] + offA[kk]);                      \
      i32x4 fa1 = *(const i32x4*)(&A1[buf][0] + offA[kk]);                      \
      i32x4 bv[2];                                                              \
      _Pragma("unroll")                                                         \
      for (int nn = 0; nn < 2; ++nn) {                                          \
        unsigned x = ((kk < 2) ? bregs[nn].x : bregs[nn].y) >> ((kk & 1) * 16); \
        x &= 0xFFFFu;                                                           \
        _Pragma("unroll")                                                       \
        for (int w = 0; w < 4; ++w) {                                           \
          unsigned nib = (x >> (4 * w)) & 0xFu;                                 \
          bv[nn][w] = (int)((nib * 0x00204081u) & 0x01010101u);                 \
        }                                                                       \
      }                                                                         \
      __builtin_amdgcn_s_setprio(1);                                            \
      _Pragma("unroll")                                                         \
      for (int nn = 0; nn < 2; ++nn) {                                          \
        acc0[nn] = __builtin_amdgcn_mfma_i32_32x32x32_i8(fa0, bv[nn], acc0[nn], 0, 0, 0); \
        acc1[nn] = __builtin_amdgcn_mfma_i32_32x32x32_i8(fa1, bv[nn], acc1[nn], 0, 0, 0); \
      }                                                                         \
      __builtin_amdgcn_s_setprio(0);                                            \
    }                                                                           \
    __builtin_amdgcn_s_barrier();                                               \
    __builtin_amdgcn_sched_barrier(0);                                          \
    if ((ks) + 2 < NKS) { STAGE((ks) + 2, buf); LDB((ks) + 2, bregs); }         \
  } while (0)

  uint2 bA[2], bB[2];
  STAGE(0, 0); LDB(0, bA);
  STAGE(1, 1); LDB(1, bB);

  for (int ks = 0; ks < NKS; ks += 2) {
    BODY(ks, 0, bA);
    BODY(ks + 1, 1, bB);
  }
#undef BODY
#undef LDB
#undef STAGE

  // C/D 32x32: col = lane&31, row = (reg&3) + 8*(reg>>2) + 4*h
#pragma unroll
  for (int nn = 0; nn < 2; ++nn) {
    int ob = gy * 128 + wr * 32;
    int cb = gx * 128 + wc * 64 + nn * 32 + l31;
#pragma unroll
    for (int reg = 0; reg < 16; ++reg) {
      int row = (reg & 3) + 8 * (reg >> 2) + 4 * h;
      int v = acc0[nn][reg] + (acc1[nn][reg] << 8);
      C[(size_t)(ob + row) * NC + cb] = (float)v * (1.0f / 32768.0f);
    }
  }
}

// ============ K3: psp+spike + fused partial Wv2 dot -> a2part ===============
__global__ void __launch_bounds__(256) k_spk1(const float* __restrict__ C,
                                              const float* __restrict__ Wv2,
                                              float* __restrict__ a2part) {
  __shared__ float tile[128 * 65];   // [t_local][ch]
  __shared__ char  spkb[128 * 68];   // [t_local][ch]
  __shared__ float w2s[O2][64];
  int og = blockIdx.x, n = blockIdx.y;
  int tid = threadIdx.x;
  for (int i = tid; i < O2 * 64; i += 256)
    w2s[i >> 6][i & 63] = Wv2[(i >> 6) * O1 + og * 64 + (i & 63)];
  float p = 0.f, r = 0.f;
  for (int tc = 0; tc < 4; ++tc) {
#pragma unroll
    for (int i = 0; i < 8; ++i) {
      int idx = i * 256 + tid;
      int row = idx >> 5, c4 = idx & 31;
      f32x4 v = *(const f32x4*)(C + (size_t)(og * 64 + row) * NC + n * TP + tc * 128 + c4 * 4);
#pragma unroll
      for (int j = 0; j < 4; ++j) tile[(c4 * 4 + j) * 65 + row] = v[j];
    }
    __syncthreads();
    if (tid < 64) {
      float pp = p, rr = r;
      for (int i = 0; i < 128; i += 8) {
        float u[8];
#pragma unroll
        for (int j = 0; j < 8; ++j) u[j] = tile[(i + j) * 65 + tid];
#pragma unroll
        for (int j = 0; j < 8; ++j) {
          pp = DSR * pp + u[j];
          float v = pp + rr;
          bool s = (v >= THETA);
          rr = DREF * (rr - (s ? REFAMP : 0.f));
          spkb[(i + j) * 68 + tid] = s ? (char)1 : (char)0;
        }
      }
      p = pp; r = rr;
    }
    __syncthreads();
    if (tid < 128) {
      float acc[O2];
#pragma unroll
      for (int o = 0; o < O2; ++o) acc[o] = 0.f;
      for (int row = 0; row < 64; ++row) {
        float s = (spkb[tid * 68 + row] != 0) ? 1.f : 0.f;
#pragma unroll
        for (int o = 0; o < O2; ++o) acc[o] = fmaf(w2s[o][row], s, acc[o]);
      }
      int tglob = tc * 128 + tid;
#pragma unroll
      for (int o = 0; o < O2; ++o)
        a2part[(((size_t)og * NB + n) * O2 + o) * TP + tglob] = acc[o];
    }
    __syncthreads();
  }
}

// ============ K4: reduce a2part -> psp+spike -> Wf -> psp+spike -> out ======
__global__ void __launch_bounds__(512) k_finish(const float* __restrict__ a2part,
                                                const float* __restrict__ s_tact,
                                                const float* __restrict__ Wf,
                                                float* __restrict__ out) {
  __shared__ float u2[TP * 12];
  __shared__ float af[TP * 21];
  int n = blockIdx.x, t = threadIdx.x;
#pragma unroll
  for (int o = 0; o < O2; ++o) {
    float s = 0.f;
#pragma unroll
    for (int og = 0; og < NB; ++og)
      s += a2part[(((size_t)og * NB + n) * O2 + o) * TP + t];
    u2[t * 12 + o] = s;
  }
  __syncthreads();
  if (t < O2) {
    float p = 0.f, r = 0.f;
    for (int i = 0; i < TT; i += 10) {
      float u[10];
#pragma unroll
      for (int j = 0; j < 10; ++j) u[j] = u2[(i + j) * 12 + t];
#pragma unroll
      for (int j = 0; j < 10; ++j) {
        p = DSR * p + u[j];
        float v = p + r;
        bool s = (v >= THETA);
        r = DREF * (r - (s ? REFAMP : 0.f));
        u2[(i + j) * 12 + t] = s ? 1.f : 0.f;
      }
    }
  }
  __syncthreads();
  if (t < TT) {
    float acc[OF];
#pragma unroll
    for (int o = 0; o < OF; ++o) acc[o] = 0.f;
    for (int f = 0; f < OT; ++f) {
      float s = s_tact[((size_t)n * OT + f) * TT + t];
#pragma unroll
      for (int o = 0; o < OF; ++o) acc[o] = fmaf(Wf[o * 60 + f], s, acc[o]);
    }
#pragma unroll
    for (int f = 0; f < O2; ++f) {
      float s = u2[t * 12 + f];
#pragma unroll
      for (int o = 0; o < OF; ++o) acc[o] = fmaf(Wf[o * 60 + OT + f], s, acc[o]);
    }
#pragma unroll
    for (int o = 0; o < OF; ++o) af[t * 21 + o] = acc[o];
  }
  __syncthreads();
  if (t < OF) {
    float p = 0.f, r = 0.f;
    float* op = out + ((size_t)n * OF + t) * TT;
    for (int i = 0; i < TT; i += 10) {
      float u[10];
#pragma unroll
      for (int j = 0; j < 10; ++j) u[j] = af[(i + j) * 21 + t];
#pragma unroll
      for (int j = 0; j < 10; ++j) {
        p = DSR * p + u[j];
        float v = p + r;
        bool s = (v >= THETA);
        r = DREF * (r - (s ? REFAMP : 0.f));
        op[i + j] = s ? 1.f : 0.f;
      }
    }
  }
}

extern "C" void kernel_launch(void* const* d_in, const int* in_sizes, int n_in,
                              void* d_out, int out_size, void* d_ws, size_t ws_size,
                              hipStream_t stream) {
  (void)in_sizes; (void)n_in; (void)out_size; (void)ws_size;
  const float* xt  = (const float*)d_in[0];
  const float* xv  = (const float*)d_in[1];
  const float* Wt  = (const float*)d_in[2];
  const float* Wv1 = (const float*)d_in[3];
  const float* Wv2 = (const float*)d_in[4];
  const float* Wf  = (const float*)d_in[5];
  float* out = (float*)d_out;

  char* ws = (char*)d_ws;
  size_t off = 0;
  auto carve = [&](size_t bytes) {
    char* p = ws + off;
    off += (bytes + 255) & ~(size_t)255;
    return p;
  };
  char*          H0    = carve((size_t)O1 * KP);
  char*          H1    = carve((size_t)O1 * KP);
  unsigned char* Bg    = (unsigned char*)carve((size_t)NKS * 8192 * 16);
  float*         a1    = (float*)carve((size_t)O1 * NC * 4);
  float*         stact = (float*)carve((size_t)NB * OT * TT * 4);
  float*         a2p   = (float*)carve((size_t)NB * NB * O2 * TP * 4);

  k_prep<<<dim3(1888), dim3(512), 0, stream>>>(xv, Wv1, xt, Wt, Bg, H0, H1, stact);
  k_gemm<<<dim3(512), dim3(512), 0, stream>>>(H0, H1, Bg, a1);
  k_spk1<<<dim3(16, NB), dim3(256), 0, stream>>>(a1, Wv2, a2p);
  k_finish<<<dim3(NB), dim3(512), 0, stream>>>(a2p, stact, Wf, out);
}